// Round 3
// baseline (19845.366 us; speedup 1.0000x reference)
//
#include <hip/hip_runtime.h>
#include <math.h>

// Speller round 2: replace contended single-counter grid barrier with a
// contention-free flag-scan barrier.
//   round-1 post-mortem: 22 us/barrier = 256 same-address atomicAdd RMWs +
//   pollers sharing the SAME 128B line as the counter. New barrier: per-WG
//   padded arrival flags (plain release stores), WG0/wave0 scans + publishes
//   gen, everyone acquire-polls gen (read-only line, no ownership ping-pong).

#define U_   512
#define S_   512
#define T_   128
#define B_   32
#define G4   2048
#define V_   46
#define NWG  256
#define FSTR 32            // flag stride in u32 = 128 B

__device__ __forceinline__ void grid_bar(unsigned* flags, unsigned* gen,
                                         unsigned seq) {
  __syncthreads();
  const int tid = threadIdx.x;
  if (blockIdx.x == 0) {
    if (tid < 64) {
      if (tid == 0)
        __hip_atomic_store(&flags[0], seq, __ATOMIC_RELAXED,
                           __HIP_MEMORY_SCOPE_AGENT);
      const int base = tid * 4;
      for (;;) {
        bool ok = true;
#pragma unroll
        for (int j = 0; j < 4; ++j) {
          unsigned v = __hip_atomic_load(&flags[(base + j) * FSTR],
                                         __ATOMIC_ACQUIRE,
                                         __HIP_MEMORY_SCOPE_AGENT);
          ok &= (v >= seq);
        }
        if (__all(ok)) break;
        __builtin_amdgcn_s_sleep(2);
      }
      if (tid == 0)
        __hip_atomic_store(gen, seq, __ATOMIC_RELEASE,
                           __HIP_MEMORY_SCOPE_AGENT);
    }
  } else {
    if (tid == 0) {
      __hip_atomic_store(&flags[blockIdx.x * FSTR], seq, __ATOMIC_RELEASE,
                         __HIP_MEMORY_SCOPE_AGENT);
      while (__hip_atomic_load(gen, __ATOMIC_ACQUIRE,
                               __HIP_MEMORY_SCOPE_AGENT) < seq)
        __builtin_amdgcn_s_sleep(8);
    }
  }
  __syncthreads();
}

// ---------------- GEMM: Z[M,2048] = A[M,512] @ W[512,2048] + b ----------------
__global__ __launch_bounds__(256) void gemm_k512(
    const float* __restrict__ A, const float* __restrict__ W,
    const float* __restrict__ b, float* __restrict__ Z) {
  const int tid = threadIdx.x;
  const int j = blockIdx.x * 1024 + tid * 4;
  const int i0 = blockIdx.y * 8;
  float4 bj = *(const float4*)(b + j);
  float4 acc[8];
#pragma unroll
  for (int r = 0; r < 8; ++r) acc[r] = bj;
  const float* Arow = A + (size_t)i0 * U_;
  for (int k = 0; k < U_; ++k) {
    float4 w = *(const float4*)(W + (size_t)k * G4 + j);
#pragma unroll
    for (int r = 0; r < 8; ++r) {
      float a = Arow[(size_t)r * U_ + k];
      acc[r].x = fmaf(a, w.x, acc[r].x);
      acc[r].y = fmaf(a, w.y, acc[r].y);
      acc[r].z = fmaf(a, w.z, acc[r].z);
      acc[r].w = fmaf(a, w.w, acc[r].w);
    }
  }
#pragma unroll
  for (int r = 0; r < 8; ++r)
    *(float4*)(Z + (size_t)(i0 + r) * G4 + j) = acc[r];
}

// ---------------- attention LSTM, cooperative ----------------
__global__ __launch_bounds__(512) void attn_coop(
    const float* __restrict__ x, const float* __restrict__ ZY,
    const float* __restrict__ R, float* __restrict__ ctxs,
    float* __restrict__ hbuf, float* __restrict__ hnbuf,
    float* __restrict__ smax, float* __restrict__ ssumg,
    float* __restrict__ ctxpart, unsigned* flags, unsigned* gen) {
  extern __shared__ float dyn[];
  float* x_s = dyn;                    // [u][67] padded
  float* R_s = dyn + 512 * 67;         // [cg][512]
  __shared__ float zp[32][8][2];
  __shared__ float hn_s[512];
  __shared__ float p_s[64];

  const int tid = threadIdx.x;
  const int bid = blockIdx.x;
  const int u0 = bid * 2;
  const int b_g = tid & 31;
  const int cg  = (tid >> 5) & 7;
  const int kh  = tid >> 8;
  const int battn = bid >> 3;
  const int sc = bid & 7;

  for (int idx = tid; idx < 64 * 512; idx += 512) {
    int sl = idx >> 9, u = idx & 511;
    x_s[u * 67 + sl] = x[((size_t)battn * S_ + sc * 64 + sl) * U_ + u];
  }
  for (int idx = tid; idx < 4096; idx += 512) {
    int k = idx >> 3, c8 = idx & 7, g = c8 >> 1, du = c8 & 1;
    R_s[c8 * 512 + k] = R[(size_t)k * G4 + g * 512 + u0 + du];
  }
  float c = 0.f, hn_reg = 0.f;
  unsigned seq = 0;
  __syncthreads();

  for (int t = 0; t < T_; ++t) {
    // ---- phase A: z = ZY + h@R, gates, hn ----
    {
      const float4* hb4 = (const float4*)(hbuf + (t & 1) * 16384);
      const float4* R4 = (const float4*)(R_s + cg * 512);
      float acc = 0.f;
      const int k40 = kh * 64;
#pragma unroll 8
      for (int k4 = 0; k4 < 64; ++k4) {
        float4 hv = hb4[(k40 + k4) * 32 + b_g];
        float4 rv = R4[k40 + k4];
        acc = fmaf(hv.x, rv.x, acc); acc = fmaf(hv.y, rv.y, acc);
        acc = fmaf(hv.z, rv.z, acc); acc = fmaf(hv.w, rv.w, acc);
      }
      zp[b_g][cg][kh] = acc;
    }
    __syncthreads();
    if (tid < 64) {
      const int b = tid >> 1, du = tid & 1;
      const float* zy = ZY + ((size_t)b * T_ + t) * G4 + u0 + du;
      float zi = zy[0]    + zp[b][0 + du][0] + zp[b][0 + du][1];
      float zf = zy[512]  + zp[b][2 + du][0] + zp[b][2 + du][1];
      float zg = zy[1024] + zp[b][4 + du][0] + zp[b][4 + du][1];
      float zo = zy[1536] + zp[b][6 + du][0] + zp[b][6 + du][1];
      float ig = 1.f / (1.f + expf(-zi));
      float fg = 1.f / (1.f + expf(-zf));
      float gg = tanhf(zg);
      float og = 1.f / (1.f + expf(-zo));
      c = fg * c + ig * gg;
      hn_reg = og * tanhf(c);
      hnbuf[b * 512 + u0 + du] = hn_reg;
    }
    grid_bar(flags, gen, ++seq);

    // ---- phase B+C: scores, local softmax, ctx partials ----
    if (tid < 128)
      ((float4*)hn_s)[tid] = ((const float4*)(hnbuf + battn * 512))[tid];
    __syncthreads();
    {
      const int wv = tid >> 6, ln = tid & 63;
      for (int si = 0; si < 8; ++si) {
        const int sl = wv * 8 + si;
        float a = 0.f;
#pragma unroll
        for (int uu = ln; uu < 512; uu += 64)
          a = fmaf(hn_s[uu], x_s[uu * 67 + sl], a);
#pragma unroll
        for (int off = 32; off; off >>= 1) a += __shfl_down(a, off);
        if (ln == 0) p_s[sl] = a;
      }
    }
    __syncthreads();
    if (tid < 64) {
      float v = p_s[tid];
      float m = v;
#pragma unroll
      for (int off = 32; off; off >>= 1) m = fmaxf(m, __shfl_down(m, off));
      m = __shfl(m, 0);
      float ex = expf(v - m);
      p_s[tid] = ex;
      float sm = ex;
#pragma unroll
      for (int off = 32; off; off >>= 1) sm += __shfl_down(sm, off);
      if (tid == 0) { smax[battn * 8 + sc] = m; ssumg[battn * 8 + sc] = sm; }
    }
    __syncthreads();
    {
      float a = 0.f;
      const float* xr = x_s + tid * 67;
#pragma unroll 8
      for (int s = 0; s < 64; ++s) a = fmaf(p_s[s], xr[s], a);
      ctxpart[((size_t)battn * 8 + sc) * 512 + tid] = a;
    }
    grid_bar(flags, gen, ++seq);

    // ---- phase D: combine slices, update carries ----
    if (tid < 64) {
      const int b = tid >> 1, du = tid & 1, u = u0 + du;
      float lm[8], gm = -INFINITY;
#pragma unroll
      for (int j = 0; j < 8; ++j) { lm[j] = smax[b * 8 + j]; gm = fmaxf(gm, lm[j]); }
      float stot = 0.f, cs = 0.f;
#pragma unroll
      for (int j = 0; j < 8; ++j) {
        float w = expf(lm[j] - gm);
        stot = fmaf(ssumg[b * 8 + j], w, stot);
        cs = fmaf(ctxpart[((size_t)b * 8 + j) * 512 + u], w, cs);
      }
      float ctxv = cs / stot;
      c += ctxv;
      float hcar = hn_reg + ctxv;
      hbuf[((t + 1) & 1) * 16384 + ((u >> 2) * 32 + b) * 4 + (u & 3)] = hcar;
      ctxs[((size_t)b * T_ + t) * U_ + u] = ctxv;
    }
    grid_bar(flags, gen, ++seq);
  }
}

// ---------------- plain LSTM, cooperative ----------------
__global__ __launch_bounds__(512) void lstm_coop(
    const float* __restrict__ Zin, const float* __restrict__ R,
    float* __restrict__ seq_out, float* __restrict__ last_out,
    float* __restrict__ hbuf, unsigned* flags, unsigned* gen) {
  extern __shared__ float dyn[];
  float* h_s = dyn;                    // 16384 floats
  float* R_s = dyn + 16384;            // [cg][512]
  __shared__ float zp[32][8][2];
  const int tid = threadIdx.x;
  const int bid = blockIdx.x;
  const int u0 = bid * 2;
  const int b_g = tid & 31, cg = (tid >> 5) & 7, kh = tid >> 8;

  for (int idx = tid; idx < 4096; idx += 512) {
    int k = idx >> 3, c8 = idx & 7, g = c8 >> 1, du = c8 & 1;
    R_s[c8 * 512 + k] = R[(size_t)k * G4 + g * 512 + u0 + du];
  }
  float c = 0.f;
  unsigned seq = 0;
  __syncthreads();

  for (int t = 0; t < T_; ++t) {
    {
      const float4* hb4 = (const float4*)(hbuf + (t & 1) * 16384);
      float4* hs4 = (float4*)h_s;
      for (int i = tid; i < 4096; i += 512) hs4[i] = hb4[i];
    }
    __syncthreads();
    {
      const float4* H4 = (const float4*)h_s;
      const float4* R4 = (const float4*)(R_s + cg * 512);
      float acc = 0.f;
      const int k40 = kh * 64;
#pragma unroll 8
      for (int k4 = 0; k4 < 64; ++k4) {
        float4 hv = H4[(k40 + k4) * 32 + b_g];
        float4 rv = R4[k40 + k4];
        acc = fmaf(hv.x, rv.x, acc); acc = fmaf(hv.y, rv.y, acc);
        acc = fmaf(hv.z, rv.z, acc); acc = fmaf(hv.w, rv.w, acc);
      }
      zp[b_g][cg][kh] = acc;
    }
    __syncthreads();
    if (tid < 64) {
      const int b = tid >> 1, du = tid & 1, u = u0 + du;
      const float* zy = Zin + ((size_t)b * T_ + t) * G4 + u0 + du;
      float zi = zy[0]    + zp[b][0 + du][0] + zp[b][0 + du][1];
      float zf = zy[512]  + zp[b][2 + du][0] + zp[b][2 + du][1];
      float zg = zy[1024] + zp[b][4 + du][0] + zp[b][4 + du][1];
      float zo = zy[1536] + zp[b][6 + du][0] + zp[b][6 + du][1];
      float ig = 1.f / (1.f + expf(-zi));
      float fg = 1.f / (1.f + expf(-zf));
      float gg = tanhf(zg);
      float og = 1.f / (1.f + expf(-zo));
      c = fg * c + ig * gg;
      float hv2 = og * tanhf(c);
      hbuf[((t + 1) & 1) * 16384 + ((u >> 2) * 32 + b) * 4 + (u & 3)] = hv2;
      if (seq_out) seq_out[((size_t)b * T_ + t) * U_ + u] = hv2;
      if (last_out && t == T_ - 1) last_out[b * U_ + u] = hv2;
    }
    grid_bar(flags, gen, ++seq);
  }
}

// ---------------- decoder ----------------
__global__ __launch_bounds__(64) void final_k(
    const float* __restrict__ hT, const float* __restrict__ Wd,
    const float* __restrict__ bd, float* __restrict__ out) {
  const int b = blockIdx.x;
  const int v = threadIdx.x;
  float acc = (v < V_) ? bd[v] : -INFINITY;
  if (v < V_) {
    for (int k = 0; k < U_; ++k)
      acc = fmaf(hT[(size_t)b * U_ + k], Wd[(size_t)k * V_ + v], acc);
  }
  float m = acc;
#pragma unroll
  for (int off = 32; off; off >>= 1) m = fmaxf(m, __shfl_down(m, off));
  m = __shfl(m, 0);
  float e = (v < V_) ? expf(acc - m) : 0.f;
  float s = e;
#pragma unroll
  for (int off = 32; off; off >>= 1) s += __shfl_down(s, off);
  s = __shfl(s, 0);
  if (v < V_) out[(size_t)b * V_ + v] = e / s;
}

extern "C" void kernel_launch(void* const* d_in, const int* in_sizes, int n_in,
                              void* d_out, int out_size, void* d_ws, size_t ws_size,
                              hipStream_t stream) {
  const float* x   = (const float*)d_in[0];
  const float* y   = (const float*)d_in[1];
  const float* W_a = (const float*)d_in[2];
  const float* R_a = (const float*)d_in[3];
  const float* b_a = (const float*)d_in[4];
  const float* W1  = (const float*)d_in[5];
  const float* R1  = (const float*)d_in[6];
  const float* b1  = (const float*)d_in[7];
  const float* W2  = (const float*)d_in[8];
  const float* R2  = (const float*)d_in[9];
  const float* b2  = (const float*)d_in[10];
  const float* Wd  = (const float*)d_in[11];
  const float* bd  = (const float*)d_in[12];
  float* out = (float*)d_out;

  float* ZBUF = (float*)d_ws;                 // 8388608 f
  float* SEQ  = ZBUF + (size_t)8388608;       // 2097152 f
  float* HBUF = SEQ + (size_t)2097152;        // 32768 f
  float* HN   = HBUF + 32768;                 // 16384 f
  float* SMAX = HN + 16384;                   // 256
  float* SSUM = SMAX + 256;                   // 256
  float* CTXP = SSUM + 256;                   // 131072
  float* HT   = CTXP + 131072;                // 16384
  unsigned* BAR = (unsigned*)(HT + 16384);    // 3 * (8192 + 64) u32

  const int BARSTRIDE = 8192 + 64;
  unsigned* FLG_A = BAR;                 unsigned* GEN_A = FLG_A + 8192;
  unsigned* FLG_1 = BAR + BARSTRIDE;     unsigned* GEN_1 = FLG_1 + 8192;
  unsigned* FLG_2 = BAR + 2 * BARSTRIDE; unsigned* GEN_2 = FLG_2 + 8192;

  const int attn_lds = (512 * 67 + 8 * 512) * 4;    // 153600 B
  const int lstm_lds = (16384 + 4096) * 4;          // 81920 B
  hipFuncSetAttribute((const void*)attn_coop,
                      hipFuncAttributeMaxDynamicSharedMemorySize, attn_lds);
  hipFuncSetAttribute((const void*)lstm_coop,
                      hipFuncAttributeMaxDynamicSharedMemorySize, lstm_lds);

  dim3 ggrid(2, 512);
  hipMemsetAsync(BAR, 0, 3 * BARSTRIDE * 4, stream);

  gemm_k512<<<ggrid, 256, 0, stream>>>(y, W_a, b_a, ZBUF);
  hipMemsetAsync(HBUF, 0, 16384 * 4, stream);
  attn_coop<<<NWG, 512, attn_lds, stream>>>(x, ZBUF, R_a, SEQ, HBUF, HN,
                                            SMAX, SSUM, CTXP, FLG_A, GEN_A);
  gemm_k512<<<ggrid, 256, 0, stream>>>(SEQ, W1, b1, ZBUF);
  hipMemsetAsync(HBUF, 0, 16384 * 4, stream);
  lstm_coop<<<NWG, 512, lstm_lds, stream>>>(ZBUF, R1, SEQ, nullptr, HBUF,
                                            FLG_1, GEN_1);
  gemm_k512<<<ggrid, 256, 0, stream>>>(SEQ, W2, b2, ZBUF);
  hipMemsetAsync(HBUF, 0, 16384 * 4, stream);
  lstm_coop<<<NWG, 512, lstm_lds, stream>>>(ZBUF, R2, nullptr, HT, HBUF,
                                            FLG_2, GEN_2);
  final_k<<<B_, 64, 0, stream>>>(HT, Wd, bd, out);
}

// Round 4
// 10244.065 us; speedup vs baseline: 1.9373x; 1.9373x over previous
//
#include <hip/hip_runtime.h>
#include <math.h>

// Speller round 3: fix the REAL barrier cost — per-iteration acquire polls.
//   r2 post-mortem: acquire-at-agent lowers to bulk L1+L2 invalidate on
//   gfx950; polling with acquire nuked the XCD L2s continuously (FETCH_SIZE
//   466 MB vs ~40 MB ideal, ~30 us/barrier). v3 barrier = ockl_grid_sync
//   pattern: RELAXED polls (agent-scope atomics bypass L2 via sc1, always
//   fresh), ONE release fence before arrival store, ONE acquire fence after
//   the spin exits.

#define U_   512
#define S_   512
#define T_   128
#define B_   32
#define G4   2048
#define V_   46
#define NWG  256
#define FSTR 32            // flag stride in u32 = 128 B

__device__ __forceinline__ void grid_bar(unsigned* flags, unsigned* gen,
                                         unsigned seq) {
  __syncthreads();
  const int tid = threadIdx.x;
  if (tid == 0) {
    __builtin_amdgcn_fence(__ATOMIC_RELEASE, "agent");
    __hip_atomic_store(&flags[blockIdx.x * FSTR], seq, __ATOMIC_RELAXED,
                       __HIP_MEMORY_SCOPE_AGENT);
  }
  if (blockIdx.x == 0) {
    if (tid < 64) {
      const int base = tid * 4;
      for (;;) {
        bool ok = true;
#pragma unroll
        for (int j = 0; j < 4; ++j) {
          unsigned v = __hip_atomic_load(&flags[(base + j) * FSTR],
                                         __ATOMIC_RELAXED,
                                         __HIP_MEMORY_SCOPE_AGENT);
          ok &= (v >= seq);
        }
        if (__all(ok)) break;
        __builtin_amdgcn_s_sleep(1);
      }
      if (tid == 0)
        __hip_atomic_store(gen, seq, __ATOMIC_RELAXED,
                           __HIP_MEMORY_SCOPE_AGENT);
    }
  } else {
    if (tid == 0) {
      while (__hip_atomic_load(gen, __ATOMIC_RELAXED,
                               __HIP_MEMORY_SCOPE_AGENT) < seq)
        __builtin_amdgcn_s_sleep(2);
    }
  }
  if (tid == 0) __builtin_amdgcn_fence(__ATOMIC_ACQUIRE, "agent");
  __syncthreads();
}

// ---------------- GEMM: Z[M,2048] = A[M,512] @ W[512,2048] + b ----------------
__global__ __launch_bounds__(256) void gemm_k512(
    const float* __restrict__ A, const float* __restrict__ W,
    const float* __restrict__ b, float* __restrict__ Z) {
  const int tid = threadIdx.x;
  const int j = blockIdx.x * 1024 + tid * 4;
  const int i0 = blockIdx.y * 8;
  float4 bj = *(const float4*)(b + j);
  float4 acc[8];
#pragma unroll
  for (int r = 0; r < 8; ++r) acc[r] = bj;
  const float* Arow = A + (size_t)i0 * U_;
  for (int k = 0; k < U_; ++k) {
    float4 w = *(const float4*)(W + (size_t)k * G4 + j);
#pragma unroll
    for (int r = 0; r < 8; ++r) {
      float a = Arow[(size_t)r * U_ + k];
      acc[r].x = fmaf(a, w.x, acc[r].x);
      acc[r].y = fmaf(a, w.y, acc[r].y);
      acc[r].z = fmaf(a, w.z, acc[r].z);
      acc[r].w = fmaf(a, w.w, acc[r].w);
    }
  }
#pragma unroll
  for (int r = 0; r < 8; ++r)
    *(float4*)(Z + (size_t)(i0 + r) * G4 + j) = acc[r];
}

// ---------------- attention LSTM, cooperative ----------------
__global__ __launch_bounds__(512) void attn_coop(
    const float* __restrict__ x, const float* __restrict__ ZY,
    const float* __restrict__ R, float* __restrict__ ctxs,
    float* __restrict__ hbuf, float* __restrict__ hnbuf,
    float* __restrict__ smax, float* __restrict__ ssumg,
    float* __restrict__ ctxpart, unsigned* flags, unsigned* gen) {
  extern __shared__ float dyn[];
  float* x_s = dyn;                    // [u][67] padded
  float* R_s = dyn + 512 * 67;         // [cg][512]
  __shared__ float zp[32][8][2];
  __shared__ float hn_s[512];
  __shared__ float p_s[64];

  const int tid = threadIdx.x;
  const int bid = blockIdx.x;
  const int u0 = bid * 2;
  const int b_g = tid & 31;
  const int cg  = (tid >> 5) & 7;
  const int kh  = tid >> 8;
  const int battn = bid >> 3;
  const int sc = bid & 7;

  for (int idx = tid; idx < 64 * 512; idx += 512) {
    int sl = idx >> 9, u = idx & 511;
    x_s[u * 67 + sl] = x[((size_t)battn * S_ + sc * 64 + sl) * U_ + u];
  }
  for (int idx = tid; idx < 4096; idx += 512) {
    int k = idx >> 3, c8 = idx & 7, g = c8 >> 1, du = c8 & 1;
    R_s[c8 * 512 + k] = R[(size_t)k * G4 + g * 512 + u0 + du];
  }
  float c = 0.f, hn_reg = 0.f;
  unsigned seq = 0;
  __syncthreads();

  for (int t = 0; t < T_; ++t) {
    // ---- phase A: z = ZY + h@R, gates, hn ----
    {
      const float4* hb4 = (const float4*)(hbuf + (t & 1) * 16384);
      const float4* R4 = (const float4*)(R_s + cg * 512);
      float acc = 0.f;
      const int k40 = kh * 64;
#pragma unroll 8
      for (int k4 = 0; k4 < 64; ++k4) {
        float4 hv = hb4[(k40 + k4) * 32 + b_g];
        float4 rv = R4[k40 + k4];
        acc = fmaf(hv.x, rv.x, acc); acc = fmaf(hv.y, rv.y, acc);
        acc = fmaf(hv.z, rv.z, acc); acc = fmaf(hv.w, rv.w, acc);
      }
      zp[b_g][cg][kh] = acc;
    }
    __syncthreads();
    if (tid < 64) {
      const int b = tid >> 1, du = tid & 1;
      const float* zy = ZY + ((size_t)b * T_ + t) * G4 + u0 + du;
      float zi = zy[0]    + zp[b][0 + du][0] + zp[b][0 + du][1];
      float zf = zy[512]  + zp[b][2 + du][0] + zp[b][2 + du][1];
      float zg = zy[1024] + zp[b][4 + du][0] + zp[b][4 + du][1];
      float zo = zy[1536] + zp[b][6 + du][0] + zp[b][6 + du][1];
      float ig = 1.f / (1.f + expf(-zi));
      float fg = 1.f / (1.f + expf(-zf));
      float gg = tanhf(zg);
      float og = 1.f / (1.f + expf(-zo));
      c = fg * c + ig * gg;
      hn_reg = og * tanhf(c);
      hnbuf[b * 512 + u0 + du] = hn_reg;
    }
    grid_bar(flags, gen, ++seq);

    // ---- phase B+C: scores, local softmax, ctx partials ----
    if (tid < 128)
      ((float4*)hn_s)[tid] = ((const float4*)(hnbuf + battn * 512))[tid];
    __syncthreads();
    {
      const int wv = tid >> 6, ln = tid & 63;
      for (int si = 0; si < 8; ++si) {
        const int sl = wv * 8 + si;
        float a = 0.f;
#pragma unroll
        for (int uu = ln; uu < 512; uu += 64)
          a = fmaf(hn_s[uu], x_s[uu * 67 + sl], a);
#pragma unroll
        for (int off = 32; off; off >>= 1) a += __shfl_down(a, off);
        if (ln == 0) p_s[sl] = a;
      }
    }
    __syncthreads();
    if (tid < 64) {
      float v = p_s[tid];
      float m = v;
#pragma unroll
      for (int off = 32; off; off >>= 1) m = fmaxf(m, __shfl_down(m, off));
      m = __shfl(m, 0);
      float ex = expf(v - m);
      p_s[tid] = ex;
      float sm = ex;
#pragma unroll
      for (int off = 32; off; off >>= 1) sm += __shfl_down(sm, off);
      if (tid == 0) { smax[battn * 8 + sc] = m; ssumg[battn * 8 + sc] = sm; }
    }
    __syncthreads();
    {
      float a = 0.f;
      const float* xr = x_s + tid * 67;
#pragma unroll 8
      for (int s = 0; s < 64; ++s) a = fmaf(p_s[s], xr[s], a);
      ctxpart[((size_t)battn * 8 + sc) * 512 + tid] = a;
    }
    grid_bar(flags, gen, ++seq);

    // ---- phase D: combine slices, update carries ----
    if (tid < 64) {
      const int b = tid >> 1, du = tid & 1, u = u0 + du;
      float lm[8], gm = -INFINITY;
#pragma unroll
      for (int j = 0; j < 8; ++j) { lm[j] = smax[b * 8 + j]; gm = fmaxf(gm, lm[j]); }
      float stot = 0.f, cs = 0.f;
#pragma unroll
      for (int j = 0; j < 8; ++j) {
        float w = expf(lm[j] - gm);
        stot = fmaf(ssumg[b * 8 + j], w, stot);
        cs = fmaf(ctxpart[((size_t)b * 8 + j) * 512 + u], w, cs);
      }
      float ctxv = cs / stot;
      c += ctxv;
      float hcar = hn_reg + ctxv;
      hbuf[((t + 1) & 1) * 16384 + ((u >> 2) * 32 + b) * 4 + (u & 3)] = hcar;
      ctxs[((size_t)b * T_ + t) * U_ + u] = ctxv;
    }
    grid_bar(flags, gen, ++seq);
  }
}

// ---------------- plain LSTM, cooperative ----------------
__global__ __launch_bounds__(512) void lstm_coop(
    const float* __restrict__ Zin, const float* __restrict__ R,
    float* __restrict__ seq_out, float* __restrict__ last_out,
    float* __restrict__ hbuf, unsigned* flags, unsigned* gen) {
  extern __shared__ float dyn[];
  float* h_s = dyn;                    // 16384 floats
  float* R_s = dyn + 16384;            // [cg][512]
  __shared__ float zp[32][8][2];
  const int tid = threadIdx.x;
  const int bid = blockIdx.x;
  const int u0 = bid * 2;
  const int b_g = tid & 31, cg = (tid >> 5) & 7, kh = tid >> 8;

  for (int idx = tid; idx < 4096; idx += 512) {
    int k = idx >> 3, c8 = idx & 7, g = c8 >> 1, du = c8 & 1;
    R_s[c8 * 512 + k] = R[(size_t)k * G4 + g * 512 + u0 + du];
  }
  float c = 0.f;
  unsigned seq = 0;
  __syncthreads();

  for (int t = 0; t < T_; ++t) {
    {
      const float4* hb4 = (const float4*)(hbuf + (t & 1) * 16384);
      float4* hs4 = (float4*)h_s;
      for (int i = tid; i < 4096; i += 512) hs4[i] = hb4[i];
    }
    __syncthreads();
    {
      const float4* H4 = (const float4*)h_s;
      const float4* R4 = (const float4*)(R_s + cg * 512);
      float acc = 0.f;
      const int k40 = kh * 64;
#pragma unroll 8
      for (int k4 = 0; k4 < 64; ++k4) {
        float4 hv = H4[(k40 + k4) * 32 + b_g];
        float4 rv = R4[k40 + k4];
        acc = fmaf(hv.x, rv.x, acc); acc = fmaf(hv.y, rv.y, acc);
        acc = fmaf(hv.z, rv.z, acc); acc = fmaf(hv.w, rv.w, acc);
      }
      zp[b_g][cg][kh] = acc;
    }
    __syncthreads();
    if (tid < 64) {
      const int b = tid >> 1, du = tid & 1, u = u0 + du;
      const float* zy = Zin + ((size_t)b * T_ + t) * G4 + u0 + du;
      float zi = zy[0]    + zp[b][0 + du][0] + zp[b][0 + du][1];
      float zf = zy[512]  + zp[b][2 + du][0] + zp[b][2 + du][1];
      float zg = zy[1024] + zp[b][4 + du][0] + zp[b][4 + du][1];
      float zo = zy[1536] + zp[b][6 + du][0] + zp[b][6 + du][1];
      float ig = 1.f / (1.f + expf(-zi));
      float fg = 1.f / (1.f + expf(-zf));
      float gg = tanhf(zg);
      float og = 1.f / (1.f + expf(-zo));
      c = fg * c + ig * gg;
      float hv2 = og * tanhf(c);
      hbuf[((t + 1) & 1) * 16384 + ((u >> 2) * 32 + b) * 4 + (u & 3)] = hv2;
      if (seq_out) seq_out[((size_t)b * T_ + t) * U_ + u] = hv2;
      if (last_out && t == T_ - 1) last_out[b * U_ + u] = hv2;
    }
    grid_bar(flags, gen, ++seq);
  }
}

// ---------------- decoder ----------------
__global__ __launch_bounds__(64) void final_k(
    const float* __restrict__ hT, const float* __restrict__ Wd,
    const float* __restrict__ bd, float* __restrict__ out) {
  const int b = blockIdx.x;
  const int v = threadIdx.x;
  float acc = (v < V_) ? bd[v] : -INFINITY;
  if (v < V_) {
    for (int k = 0; k < U_; ++k)
      acc = fmaf(hT[(size_t)b * U_ + k], Wd[(size_t)k * V_ + v], acc);
  }
  float m = acc;
#pragma unroll
  for (int off = 32; off; off >>= 1) m = fmaxf(m, __shfl_down(m, off));
  m = __shfl(m, 0);
  float e = (v < V_) ? expf(acc - m) : 0.f;
  float s = e;
#pragma unroll
  for (int off = 32; off; off >>= 1) s += __shfl_down(s, off);
  s = __shfl(s, 0);
  if (v < V_) out[(size_t)b * V_ + v] = e / s;
}

extern "C" void kernel_launch(void* const* d_in, const int* in_sizes, int n_in,
                              void* d_out, int out_size, void* d_ws, size_t ws_size,
                              hipStream_t stream) {
  const float* x   = (const float*)d_in[0];
  const float* y   = (const float*)d_in[1];
  const float* W_a = (const float*)d_in[2];
  const float* R_a = (const float*)d_in[3];
  const float* b_a = (const float*)d_in[4];
  const float* W1  = (const float*)d_in[5];
  const float* R1  = (const float*)d_in[6];
  const float* b1  = (const float*)d_in[7];
  const float* W2  = (const float*)d_in[8];
  const float* R2  = (const float*)d_in[9];
  const float* b2  = (const float*)d_in[10];
  const float* Wd  = (const float*)d_in[11];
  const float* bd  = (const float*)d_in[12];
  float* out = (float*)d_out;

  float* ZBUF = (float*)d_ws;                 // 8388608 f
  float* SEQ  = ZBUF + (size_t)8388608;       // 2097152 f
  float* HBUF = SEQ + (size_t)2097152;        // 32768 f
  float* HN   = HBUF + 32768;                 // 16384 f
  float* SMAX = HN + 16384;                   // 256
  float* SSUM = SMAX + 256;                   // 256
  float* CTXP = SSUM + 256;                   // 131072
  float* HT   = CTXP + 131072;                // 16384
  unsigned* BAR = (unsigned*)(HT + 16384);    // 3 * (8192 + 64) u32

  const int BARSTRIDE = 8192 + 64;
  unsigned* FLG_A = BAR;                 unsigned* GEN_A = FLG_A + 8192;
  unsigned* FLG_1 = BAR + BARSTRIDE;     unsigned* GEN_1 = FLG_1 + 8192;
  unsigned* FLG_2 = BAR + 2 * BARSTRIDE; unsigned* GEN_2 = FLG_2 + 8192;

  const int attn_lds = (512 * 67 + 8 * 512) * 4;    // 153600 B
  const int lstm_lds = (16384 + 4096) * 4;          // 81920 B
  hipFuncSetAttribute((const void*)attn_coop,
                      hipFuncAttributeMaxDynamicSharedMemorySize, attn_lds);
  hipFuncSetAttribute((const void*)lstm_coop,
                      hipFuncAttributeMaxDynamicSharedMemorySize, lstm_lds);

  dim3 ggrid(2, 512);
  hipMemsetAsync(BAR, 0, 3 * BARSTRIDE * 4, stream);

  gemm_k512<<<ggrid, 256, 0, stream>>>(y, W_a, b_a, ZBUF);
  hipMemsetAsync(HBUF, 0, 16384 * 4, stream);
  attn_coop<<<NWG, 512, attn_lds, stream>>>(x, ZBUF, R_a, SEQ, HBUF, HN,
                                            SMAX, SSUM, CTXP, FLG_A, GEN_A);
  gemm_k512<<<ggrid, 256, 0, stream>>>(SEQ, W1, b1, ZBUF);
  hipMemsetAsync(HBUF, 0, 16384 * 4, stream);
  lstm_coop<<<NWG, 512, lstm_lds, stream>>>(ZBUF, R1, SEQ, nullptr, HBUF,
                                            FLG_1, GEN_1);
  gemm_k512<<<ggrid, 256, 0, stream>>>(SEQ, W2, b2, ZBUF);
  hipMemsetAsync(HBUF, 0, 16384 * 4, stream);
  lstm_coop<<<NWG, 512, lstm_lds, stream>>>(ZBUF, R2, nullptr, HT, HBUF,
                                            FLG_2, GEN_2);
  final_k<<<B_, 64, 0, stream>>>(HT, Wd, bd, out);
}

// Round 5
// 6713.905 us; speedup vs baseline: 2.9559x; 1.5258x over previous
//
#include <hip/hip_runtime.h>
#include <math.h>

// Speller round 4: fence-FREE grid sync via device-coherent (sc1) data.
//   r3 post-mortem: barrier protocol was fine; the per-barrier acquire/release
//   FENCES (buffer_inv / wbl2 at agent scope) nuked all 8 XCD L2s every step
//   (attn FETCH stuck at 466 MB = 3.6 MB/step of L2 refill, 52.7 us/step).
//   v4: all cross-WG data (h carry, hn, softmax partials, ctx partials) moves
//   to RELAXED agent-scope atomics (sc1, L2-bypassing, cross-XCD coherent —
//   proven by the working flag polls). No fences anywhere -> L2 never
//   invalidated -> R/ZY/x stay cache-resident across all 128 steps.
//   attn: R_a read per-step from warm L2 via pre-transposed RT (16 KB/WG,
//   lane-broadcast float4); freed 16 KB LDS holds an h-stage.

#define U_   512
#define S_   512
#define T_   128
#define B_   32
#define G4   2048
#define V_   46
#define NWG  256
#define FSTR 32            // flag stride in u32 = 128 B

#define AT_LD(p)     __hip_atomic_load((p), __ATOMIC_RELAXED, __HIP_MEMORY_SCOPE_AGENT)
#define AT_ST(p, v)  __hip_atomic_store((p), (v), __ATOMIC_RELAXED, __HIP_MEMORY_SCOPE_AGENT)

__device__ __forceinline__ void grid_sync(unsigned* flags, unsigned* gen,
                                          unsigned seq) {
  __syncthreads();   // drains each wave's outstanding stores before arrival
  const int tid = threadIdx.x;
  if (blockIdx.x == 0) {
    if (tid < 64) {
      if (tid == 0) AT_ST(&flags[0], seq);
      const int base = tid * 4;
      for (;;) {
        bool ok = true;
#pragma unroll
        for (int j = 0; j < 4; ++j)
          ok &= (AT_LD(&flags[(base + j) * FSTR]) >= seq);
        if (__all(ok)) break;
        __builtin_amdgcn_s_sleep(1);
      }
      if (tid == 0) AT_ST(gen, seq);
    }
  } else {
    if (tid == 0) {
      AT_ST(&flags[blockIdx.x * FSTR], seq);
      while (AT_LD(gen) < seq) __builtin_amdgcn_s_sleep(1);
    }
  }
  __syncthreads();
}

// ---------------- GEMM: Z[M,2048] = A[M,512] @ W[512,2048] + b ----------------
__global__ __launch_bounds__(256) void gemm_k512(
    const float* __restrict__ A, const float* __restrict__ W,
    const float* __restrict__ b, float* __restrict__ Z) {
  const int tid = threadIdx.x;
  const int j = blockIdx.x * 1024 + tid * 4;
  const int i0 = blockIdx.y * 8;
  float4 bj = *(const float4*)(b + j);
  float4 acc[8];
#pragma unroll
  for (int r = 0; r < 8; ++r) acc[r] = bj;
  const float* Arow = A + (size_t)i0 * U_;
  for (int k = 0; k < U_; ++k) {
    float4 w = *(const float4*)(W + (size_t)k * G4 + j);
#pragma unroll
    for (int r = 0; r < 8; ++r) {
      float a = Arow[(size_t)r * U_ + k];
      acc[r].x = fmaf(a, w.x, acc[r].x);
      acc[r].y = fmaf(a, w.y, acc[r].y);
      acc[r].z = fmaf(a, w.z, acc[r].z);
      acc[r].w = fmaf(a, w.w, acc[r].w);
    }
  }
#pragma unroll
  for (int r = 0; r < 8; ++r)
    *(float4*)(Z + (size_t)(i0 + r) * G4 + j) = acc[r];
}

// ---------------- transpose R[512][2048] -> RT[2048][512] ----------------
__global__ __launch_bounds__(256) void transpose_R(
    const float* __restrict__ R, float* __restrict__ RT) {
  __shared__ float tile[64][65];
  const int c0 = blockIdx.x * 64, k0 = blockIdx.y * 64;
  const int tc = threadIdx.x & 63, tr = threadIdx.x >> 6;
  for (int r = tr; r < 64; r += 4)
    tile[r][tc] = R[(size_t)(k0 + r) * G4 + c0 + tc];
  __syncthreads();
  for (int r = tr; r < 64; r += 4)
    RT[(size_t)(c0 + r) * 512 + k0 + tc] = tile[tc][r];
}

// ---------------- attention LSTM, cooperative, fence-free ----------------
// dyn LDS: x_s [512][65] (133120 B) + h_st 4096 f (16384 B) = 149504 B
__global__ __launch_bounds__(512) void attn_coop(
    const float* __restrict__ x, const float* __restrict__ ZY,
    const float* __restrict__ RT, float* __restrict__ ctxs,
    float* hbuf, float* hnbuf, float* smax, float* ssumg,
    float* ctxpart, unsigned* flags, unsigned* gen) {
  extern __shared__ float dyn[];
  float* x_s  = dyn;                 // [u][65], conflict-free (65%32==1)
  float* h_st = dyn + 512 * 65;      // [k/4][b][4]
  __shared__ float zp[32][8][2];
  __shared__ float hn_s[512];
  __shared__ float p_s[64];

  const int tid = threadIdx.x;
  const int bid = blockIdx.x;
  const int u0 = bid * 2;
  const int b_g = tid & 31;
  const int cg  = (tid >> 5) & 7;
  const int kh  = tid >> 8;
  const int battn = bid >> 3;
  const int sc = bid & 7;
  const int col = (cg >> 1) * 512 + u0 + (cg & 1);

  for (int idx = tid; idx < 64 * 512; idx += 512) {
    int sl = idx >> 9, u = idx & 511;
    x_s[u * 65 + sl] = x[((size_t)battn * S_ + sc * 64 + sl) * U_ + u];
  }
  float c = 0.f, hn_reg = 0.f;
  unsigned seq = 0;
  __syncthreads();

  for (int t = 0; t < T_; ++t) {
    // ---- stage h (sc1 -> LDS), then GEMV from LDS + RT(L2) ----
    {
      float* hb = hbuf + (t & 1) * 16384;
      for (int i = tid; i < 16384; i += 512) h_st[i] = AT_LD(&hb[i]);
    }
    __syncthreads();
    {
      const float4* H4 = (const float4*)h_st;
      const float4* R4 = (const float4*)(RT + (size_t)col * 512) + kh * 64;
      float acc = 0.f;
      const int k40 = kh * 64;
#pragma unroll 8
      for (int k4 = 0; k4 < 64; ++k4) {
        float4 hv = H4[(k40 + k4) * 32 + b_g];
        float4 rv = R4[k4];
        acc = fmaf(hv.x, rv.x, acc); acc = fmaf(hv.y, rv.y, acc);
        acc = fmaf(hv.z, rv.z, acc); acc = fmaf(hv.w, rv.w, acc);
      }
      zp[b_g][cg][kh] = acc;
    }
    __syncthreads();
    if (tid < 64) {
      const int b = tid >> 1, du = tid & 1;
      const float* zy = ZY + ((size_t)b * T_ + t) * G4 + u0 + du;
      float zi = zy[0]    + zp[b][0 + du][0] + zp[b][0 + du][1];
      float zf = zy[512]  + zp[b][2 + du][0] + zp[b][2 + du][1];
      float zg = zy[1024] + zp[b][4 + du][0] + zp[b][4 + du][1];
      float zo = zy[1536] + zp[b][6 + du][0] + zp[b][6 + du][1];
      float ig = 1.f / (1.f + expf(-zi));
      float fg = 1.f / (1.f + expf(-zf));
      float gg = tanhf(zg);
      float og = 1.f / (1.f + expf(-zo));
      c = fg * c + ig * gg;
      hn_reg = og * tanhf(c);
      AT_ST(&hnbuf[b * 512 + u0 + du], hn_reg);
    }
    grid_sync(flags, gen, ++seq);

    // ---- scores, local softmax, ctx partials ----
    hn_s[tid] = AT_LD(&hnbuf[battn * 512 + tid]);
    __syncthreads();
    {
      const int wv = tid >> 6, ln = tid & 63;
      for (int si = 0; si < 8; ++si) {
        const int sl = wv * 8 + si;
        float a = 0.f;
#pragma unroll
        for (int uu = ln; uu < 512; uu += 64)
          a = fmaf(hn_s[uu], x_s[uu * 65 + sl], a);
#pragma unroll
        for (int off = 32; off; off >>= 1) a += __shfl_down(a, off);
        if (ln == 0) p_s[sl] = a;
      }
    }
    __syncthreads();
    if (tid < 64) {
      float v = p_s[tid];
      float m = v;
#pragma unroll
      for (int off = 32; off; off >>= 1) m = fmaxf(m, __shfl_down(m, off));
      m = __shfl(m, 0);
      float ex = expf(v - m);
      p_s[tid] = ex;
      float sm = ex;
#pragma unroll
      for (int off = 32; off; off >>= 1) sm += __shfl_down(sm, off);
      if (tid == 0) {
        AT_ST(&smax[battn * 8 + sc], m);
        AT_ST(&ssumg[battn * 8 + sc], sm);
      }
    }
    __syncthreads();
    {
      float a = 0.f;
      const float* xr = x_s + tid * 65;
#pragma unroll 8
      for (int s = 0; s < 64; ++s) a = fmaf(p_s[s], xr[s], a);
      AT_ST(&ctxpart[((size_t)battn * 8 + sc) * 512 + tid], a);
    }
    grid_sync(flags, gen, ++seq);

    // ---- combine slices, update carries ----
    if (tid < 64) {
      const int b = tid >> 1, du = tid & 1, u = u0 + du;
      float lm[8], gm = -INFINITY;
#pragma unroll
      for (int j = 0; j < 8; ++j) {
        lm[j] = AT_LD(&smax[b * 8 + j]);
        gm = fmaxf(gm, lm[j]);
      }
      float stot = 0.f, cs = 0.f;
#pragma unroll
      for (int j = 0; j < 8; ++j) {
        float w = expf(lm[j] - gm);
        stot = fmaf(AT_LD(&ssumg[b * 8 + j]), w, stot);
        cs = fmaf(AT_LD(&ctxpart[((size_t)b * 8 + j) * 512 + u]), w, cs);
      }
      float ctxv = cs / stot;
      c += ctxv;
      float hcar = hn_reg + ctxv;
      AT_ST(&hbuf[((t + 1) & 1) * 16384 + ((u >> 2) * 32 + b) * 4 + (u & 3)],
            hcar);
      ctxs[((size_t)b * T_ + t) * U_ + u] = ctxv;
    }
    grid_sync(flags, gen, ++seq);
  }
}

// ---------------- plain LSTM, cooperative, fence-free ----------------
// dyn LDS: h_s 16384 f + R_s 4096 f = 81920 B
__global__ __launch_bounds__(512) void lstm_coop(
    const float* __restrict__ Zin, const float* __restrict__ R,
    float* __restrict__ seq_out, float* __restrict__ last_out,
    float* hbuf, unsigned* flags, unsigned* gen) {
  extern __shared__ float dyn[];
  float* h_s = dyn;                  // [k/4][b][4]
  float* R_s = dyn + 16384;          // [cg][512]
  __shared__ float zp[32][8][2];
  const int tid = threadIdx.x;
  const int bid = blockIdx.x;
  const int u0 = bid * 2;
  const int b_g = tid & 31, cg = (tid >> 5) & 7, kh = tid >> 8;

  for (int idx = tid; idx < 4096; idx += 512) {
    int k = idx >> 3, c8 = idx & 7, g = c8 >> 1, du = c8 & 1;
    R_s[c8 * 512 + k] = R[(size_t)k * G4 + g * 512 + u0 + du];
  }
  float c = 0.f;
  unsigned seq = 0;
  __syncthreads();

  for (int t = 0; t < T_; ++t) {
    {
      float* hb = hbuf + (t & 1) * 16384;
      for (int i = tid; i < 16384; i += 512) h_s[i] = AT_LD(&hb[i]);
    }
    __syncthreads();
    {
      const float4* H4 = (const float4*)h_s;
      const float4* R4 = (const float4*)(R_s + cg * 512);
      float acc = 0.f;
      const int k40 = kh * 64;
#pragma unroll 8
      for (int k4 = 0; k4 < 64; ++k4) {
        float4 hv = H4[(k40 + k4) * 32 + b_g];
        float4 rv = R4[k40 + k4];
        acc = fmaf(hv.x, rv.x, acc); acc = fmaf(hv.y, rv.y, acc);
        acc = fmaf(hv.z, rv.z, acc); acc = fmaf(hv.w, rv.w, acc);
      }
      zp[b_g][cg][kh] = acc;
    }
    __syncthreads();
    if (tid < 64) {
      const int b = tid >> 1, du = tid & 1, u = u0 + du;
      const float* zy = Zin + ((size_t)b * T_ + t) * G4 + u0 + du;
      float zi = zy[0]    + zp[b][0 + du][0] + zp[b][0 + du][1];
      float zf = zy[512]  + zp[b][2 + du][0] + zp[b][2 + du][1];
      float zg = zy[1024] + zp[b][4 + du][0] + zp[b][4 + du][1];
      float zo = zy[1536] + zp[b][6 + du][0] + zp[b][6 + du][1];
      float ig = 1.f / (1.f + expf(-zi));
      float fg = 1.f / (1.f + expf(-zf));
      float gg = tanhf(zg);
      float og = 1.f / (1.f + expf(-zo));
      c = fg * c + ig * gg;
      float hv2 = og * tanhf(c);
      AT_ST(&hbuf[((t + 1) & 1) * 16384 + ((u >> 2) * 32 + b) * 4 + (u & 3)],
            hv2);
      if (seq_out) seq_out[((size_t)b * T_ + t) * U_ + u] = hv2;
      if (last_out && t == T_ - 1) last_out[b * U_ + u] = hv2;
    }
    grid_sync(flags, gen, ++seq);
  }
}

// ---------------- decoder ----------------
__global__ __launch_bounds__(64) void final_k(
    const float* __restrict__ hT, const float* __restrict__ Wd,
    const float* __restrict__ bd, float* __restrict__ out) {
  const int b = blockIdx.x;
  const int v = threadIdx.x;
  float acc = (v < V_) ? bd[v] : -INFINITY;
  if (v < V_) {
    for (int k = 0; k < U_; ++k)
      acc = fmaf(hT[(size_t)b * U_ + k], Wd[(size_t)k * V_ + v], acc);
  }
  float m = acc;
#pragma unroll
  for (int off = 32; off; off >>= 1) m = fmaxf(m, __shfl_down(m, off));
  m = __shfl(m, 0);
  float e = (v < V_) ? expf(acc - m) : 0.f;
  float s = e;
#pragma unroll
  for (int off = 32; off; off >>= 1) s += __shfl_down(s, off);
  s = __shfl(s, 0);
  if (v < V_) out[(size_t)b * V_ + v] = e / s;
}

extern "C" void kernel_launch(void* const* d_in, const int* in_sizes, int n_in,
                              void* d_out, int out_size, void* d_ws, size_t ws_size,
                              hipStream_t stream) {
  const float* x   = (const float*)d_in[0];
  const float* y   = (const float*)d_in[1];
  const float* W_a = (const float*)d_in[2];
  const float* R_a = (const float*)d_in[3];
  const float* b_a = (const float*)d_in[4];
  const float* W1  = (const float*)d_in[5];
  const float* R1  = (const float*)d_in[6];
  const float* b1  = (const float*)d_in[7];
  const float* W2  = (const float*)d_in[8];
  const float* R2  = (const float*)d_in[9];
  const float* b2  = (const float*)d_in[10];
  const float* Wd  = (const float*)d_in[11];
  const float* bd  = (const float*)d_in[12];
  float* out = (float*)d_out;

  float* ZBUF = (float*)d_ws;                 // 8388608 f
  float* SEQ  = ZBUF + (size_t)8388608;       // 2097152 f
  float* RT   = SEQ + (size_t)2097152;        // 1048576 f
  float* HBUF = RT + (size_t)1048576;         // 32768 f
  float* HN   = HBUF + 32768;                 // 16384 f
  float* SMAX = HN + 16384;                   // 256
  float* SSUM = SMAX + 256;                   // 256
  float* CTXP = SSUM + 256;                   // 131072
  float* HT   = CTXP + 131072;                // 16384
  unsigned* BAR = (unsigned*)(HT + 16384);    // 3 * (8192 + 64) u32

  const int BARSTRIDE = 8192 + 64;
  unsigned* FLG_A = BAR;                 unsigned* GEN_A = FLG_A + 8192;
  unsigned* FLG_1 = BAR + BARSTRIDE;     unsigned* GEN_1 = FLG_1 + 8192;
  unsigned* FLG_2 = BAR + 2 * BARSTRIDE; unsigned* GEN_2 = FLG_2 + 8192;

  const int attn_lds = (512 * 65 + 4096) * 4;       // 149504 B
  const int lstm_lds = (16384 + 4096) * 4;          // 81920 B
  hipFuncSetAttribute((const void*)attn_coop,
                      hipFuncAttributeMaxDynamicSharedMemorySize, attn_lds);
  hipFuncSetAttribute((const void*)lstm_coop,
                      hipFuncAttributeMaxDynamicSharedMemorySize, lstm_lds);

  dim3 ggrid(2, 512);
  hipMemsetAsync(BAR, 0, 3 * BARSTRIDE * 4, stream);

  gemm_k512<<<ggrid, 256, 0, stream>>>(y, W_a, b_a, ZBUF);
  transpose_R<<<dim3(32, 8), 256, 0, stream>>>(R_a, RT);
  hipMemsetAsync(HBUF, 0, 16384 * 4, stream);
  attn_coop<<<NWG, 512, attn_lds, stream>>>(x, ZBUF, RT, SEQ, HBUF, HN,
                                            SMAX, SSUM, CTXP, FLG_A, GEN_A);
  gemm_k512<<<ggrid, 256, 0, stream>>>(SEQ, W1, b1, ZBUF);
  hipMemsetAsync(HBUF, 0, 16384 * 4, stream);
  lstm_coop<<<NWG, 512, lstm_lds, stream>>>(ZBUF, R1, SEQ, nullptr, HBUF,
                                            FLG_1, GEN_1);
  gemm_k512<<<ggrid, 256, 0, stream>>>(SEQ, W2, b2, ZBUF);
  hipMemsetAsync(HBUF, 0, 16384 * 4, stream);
  lstm_coop<<<NWG, 512, lstm_lds, stream>>>(ZBUF, R2, nullptr, HT, HBUF,
                                            FLG_2, GEN_2);
  final_k<<<B_, 64, 0, stream>>>(HT, Wd, bd, out);
}

// Round 6
// 4614.875 us; speedup vs baseline: 4.3003x; 1.4548x over previous
//
#include <hip/hip_runtime.h>
#include <math.h>

// Speller round 5: batch-group decoupling.
//   r4 post-mortem: barrier ~4 us (256-WG span), h-staging ~9 us (every WG
//   sc1-reads the FULL 64 KB h each step = 16 MB/step at the coherence point).
//   v5: 8 independent groups x 32 WGs, each owns 4 batches. Group-local
//   barriers (32 arrivals, independent drift), staging 8 KB/WG (2 MB/step).
//   attn reads R from L2 (pre-transposed RT, fits XCD L2, read-only);
//   lstm keeps R in LDS ([64][516] pad: conflict-free float4 reads).

#define U_   512
#define S_   512
#define T_   128
#define B_   32
#define G4   2048
#define V_   46
#define NWG  256
#define FSTR 32            // flag stride in u32 = 128 B

#define AT_LD(p)     __hip_atomic_load((p), __ATOMIC_RELAXED, __HIP_MEMORY_SCOPE_AGENT)
#define AT_ST(p, v)  __hip_atomic_store((p), (v), __ATOMIC_RELAXED, __HIP_MEMORY_SCOPE_AGENT)

__device__ __forceinline__ void group_bar(unsigned* gflags, unsigned* ggen,
                                          unsigned seq) {
  __syncthreads();   // all waves' stores issued before arrival
  const int tid = threadIdx.x;
  const int wgid = blockIdx.x & 31;
  if (wgid == 0) {
    if (tid < 64) {
      if (tid == 0) AT_ST(&gflags[0], seq);
      const int slot = tid & 31;       // 2 lanes per flag, harmless
      while (!__all(AT_LD(&gflags[slot * FSTR]) >= seq))
        __builtin_amdgcn_s_sleep(1);
      if (tid == 0) AT_ST(ggen, seq);
    }
  } else {
    if (tid == 0) {
      AT_ST(&gflags[wgid * FSTR], seq);
      while (AT_LD(ggen) < seq) __builtin_amdgcn_s_sleep(1);
    }
  }
  __syncthreads();
}

// ---------------- GEMM: Z[M,2048] = A[M,512] @ W[512,2048] + b ----------------
__global__ __launch_bounds__(256) void gemm_k512(
    const float* __restrict__ A, const float* __restrict__ W,
    const float* __restrict__ b, float* __restrict__ Z) {
  const int tid = threadIdx.x;
  const int j = blockIdx.x * 1024 + tid * 4;
  const int i0 = blockIdx.y * 8;
  float4 bj = *(const float4*)(b + j);
  float4 acc[8];
#pragma unroll
  for (int r = 0; r < 8; ++r) acc[r] = bj;
  const float* Arow = A + (size_t)i0 * U_;
  for (int k = 0; k < U_; ++k) {
    float4 w = *(const float4*)(W + (size_t)k * G4 + j);
#pragma unroll
    for (int r = 0; r < 8; ++r) {
      float a = Arow[(size_t)r * U_ + k];
      acc[r].x = fmaf(a, w.x, acc[r].x);
      acc[r].y = fmaf(a, w.y, acc[r].y);
      acc[r].z = fmaf(a, w.z, acc[r].z);
      acc[r].w = fmaf(a, w.w, acc[r].w);
    }
  }
#pragma unroll
  for (int r = 0; r < 8; ++r)
    *(float4*)(Z + (size_t)(i0 + r) * G4 + j) = acc[r];
}

// ---------------- transpose R[512][2048] -> RT[2048][512] ----------------
__global__ __launch_bounds__(256) void transpose_R(
    const float* __restrict__ R, float* __restrict__ RT) {
  __shared__ float tile[64][65];
  const int c0 = blockIdx.x * 64, k0 = blockIdx.y * 64;
  const int tc = threadIdx.x & 63, tr = threadIdx.x >> 6;
  for (int r = tr; r < 64; r += 4)
    tile[r][tc] = R[(size_t)(k0 + r) * G4 + c0 + tc];
  __syncthreads();
  for (int r = tr; r < 64; r += 4)
    RT[(size_t)(c0 + r) * 512 + k0 + tc] = tile[tc][r];
}

// ---------------- attention LSTM: 8 groups x 32 WGs, 4 batches/group ------
// dyn LDS: x_s [512][65] + h_st [4][516]  = 141376 B
__global__ __launch_bounds__(512) void attn_coop(
    const float* __restrict__ x, const float* __restrict__ ZY,
    const float* __restrict__ RT, float* __restrict__ ctxs,
    float* hbuf, float* hnbuf, float* smax, float* ssumg,
    float* ctxpart, unsigned* flags, unsigned* gen) {
  extern __shared__ float dyn[];
  float* x_s  = dyn;                 // [u][65], conflict-free
  float* h_st = dyn + 512 * 65;      // [b_l][516]
  __shared__ float zp[4][64][2];
  __shared__ float hn_s[512];
  __shared__ float p_s[64];

  const int tid = threadIdx.x;
  const int bid = blockIdx.x;
  const int g    = bid >> 5;
  const int wgid = bid & 31;
  const int u0   = wgid * 16;
  // GEMV role mapping: 64 cols x 4 batches x 2 k-halves
  const int kh  = tid & 1;
  const int b_l = (tid >> 1) & 3;
  const int col = tid >> 3;                       // 0..63
  const int zcol = (col >> 4) * 512 + u0 + (col & 15);
  // attention role mapping
  const int b_att = 4 * g + (wgid >> 3);
  const int sc = wgid & 7;
  unsigned* gflags = flags + g * 32 * FSTR;
  unsigned* ggen   = gen + g * FSTR;

  for (int idx = tid; idx < 64 * 512; idx += 512) {
    int sl = idx >> 9, u = idx & 511;
    x_s[u * 65 + sl] = x[((size_t)b_att * S_ + sc * 64 + sl) * U_ + u];
  }
  float c = 0.f, hn_reg = 0.f;
  unsigned seq = 0;
  __syncthreads();

  for (int t = 0; t < T_; ++t) {
    // ---- stage h (8 KB, group-local batches) ----
    {
      const float* hb = hbuf + (t & 1) * 16384 + 4 * g * 512;
      for (int i = tid; i < 2048; i += 512)
        h_st[(i >> 9) * 516 + (i & 511)] = AT_LD(&hb[i]);
    }
    __syncthreads();
    // ---- GEMV: z-partial from h(LDS) x RT(L2) ----
    {
      const float4* H4 = (const float4*)(h_st + b_l * 516 + kh * 256);
      const float4* R4 = (const float4*)(RT + (size_t)zcol * 512 + kh * 256);
      float acc = 0.f;
#pragma unroll 8
      for (int i = 0; i < 64; ++i) {
        float4 hv = H4[i];
        float4 rv = R4[i];
        acc = fmaf(hv.x, rv.x, acc); acc = fmaf(hv.y, rv.y, acc);
        acc = fmaf(hv.z, rv.z, acc); acc = fmaf(hv.w, rv.w, acc);
      }
      zp[b_l][col][kh] = acc;
    }
    __syncthreads();
    if (tid < 64) {
      const int bb = tid >> 4, uu = tid & 15;
      const int b = 4 * g + bb, u = u0 + uu;
      const float* zy = ZY + ((size_t)b * T_ + t) * G4 + u;
      float zi = zy[0]    + zp[bb][uu][0]      + zp[bb][uu][1];
      float zf = zy[512]  + zp[bb][16 + uu][0] + zp[bb][16 + uu][1];
      float zg = zy[1024] + zp[bb][32 + uu][0] + zp[bb][32 + uu][1];
      float zo = zy[1536] + zp[bb][48 + uu][0] + zp[bb][48 + uu][1];
      float ig = 1.f / (1.f + expf(-zi));
      float fg = 1.f / (1.f + expf(-zf));
      float gg = tanhf(zg);
      float og = 1.f / (1.f + expf(-zo));
      c = fg * c + ig * gg;
      hn_reg = og * tanhf(c);
      AT_ST(&hnbuf[b * 512 + u], hn_reg);
    }
    group_bar(gflags, ggen, ++seq);

    // ---- scores, local softmax, ctx partials ----
    hn_s[tid] = AT_LD(&hnbuf[b_att * 512 + tid]);
    __syncthreads();
    {
      const int wv = tid >> 6, ln = tid & 63;
      for (int si = 0; si < 8; ++si) {
        const int sl = wv * 8 + si;
        float a = 0.f;
#pragma unroll
        for (int uu = ln; uu < 512; uu += 64)
          a = fmaf(hn_s[uu], x_s[uu * 65 + sl], a);
#pragma unroll
        for (int off = 32; off; off >>= 1) a += __shfl_down(a, off);
        if (ln == 0) p_s[sl] = a;
      }
    }
    __syncthreads();
    if (tid < 64) {
      float v = p_s[tid];
      float m = v;
#pragma unroll
      for (int off = 32; off; off >>= 1) m = fmaxf(m, __shfl_down(m, off));
      m = __shfl(m, 0);
      float ex = expf(v - m);
      p_s[tid] = ex;
      float sm = ex;
#pragma unroll
      for (int off = 32; off; off >>= 1) sm += __shfl_down(sm, off);
      if (tid == 0) {
        AT_ST(&smax[b_att * 8 + sc], m);
        AT_ST(&ssumg[b_att * 8 + sc], sm);
      }
    }
    __syncthreads();
    {
      float a = 0.f;
      const float* xr = x_s + tid * 65;
#pragma unroll 8
      for (int s = 0; s < 64; ++s) a = fmaf(p_s[s], xr[s], a);
      AT_ST(&ctxpart[((size_t)b_att * 8 + sc) * 512 + tid], a);
    }
    group_bar(gflags, ggen, ++seq);

    // ---- combine slices, update carries (same thread as gates) ----
    if (tid < 64) {
      const int bb = tid >> 4, uu = tid & 15;
      const int b = 4 * g + bb, u = u0 + uu;
      float lm[8], gm = -INFINITY;
#pragma unroll
      for (int j = 0; j < 8; ++j) {
        lm[j] = AT_LD(&smax[b * 8 + j]);
        gm = fmaxf(gm, lm[j]);
      }
      float stot = 0.f, cs = 0.f;
#pragma unroll
      for (int j = 0; j < 8; ++j) {
        float w = expf(lm[j] - gm);
        stot = fmaf(AT_LD(&ssumg[b * 8 + j]), w, stot);
        cs = fmaf(AT_LD(&ctxpart[((size_t)b * 8 + j) * 512 + u]), w, cs);
      }
      float ctxv = cs / stot;
      c += ctxv;
      float hcar = hn_reg + ctxv;
      AT_ST(&hbuf[((t + 1) & 1) * 16384 + b * 512 + u], hcar);
      ctxs[((size_t)b * T_ + t) * U_ + u] = ctxv;
    }
    group_bar(gflags, ggen, ++seq);
  }
}

// ---------------- plain LSTM: 8 groups x 32 WGs ----------------
// dyn LDS: R_s [64][516] + h_st [4][516] = 140352 B
__global__ __launch_bounds__(512) void lstm_coop(
    const float* __restrict__ Zin, const float* __restrict__ R,
    float* __restrict__ seq_out, float* __restrict__ last_out,
    float* hbuf, unsigned* flags, unsigned* gen) {
  extern __shared__ float dyn[];
  float* R_s  = dyn;                 // [col][516]
  float* h_st = dyn + 64 * 516;      // [b_l][516]
  __shared__ float zp[4][64][2];
  const int tid = threadIdx.x;
  const int bid = blockIdx.x;
  const int g    = bid >> 5;
  const int wgid = bid & 31;
  const int u0   = wgid * 16;
  const int kh  = tid & 1;
  const int b_l = (tid >> 1) & 3;
  const int col = tid >> 3;
  unsigned* gflags = flags + g * 32 * FSTR;
  unsigned* ggen   = gen + g * FSTR;

  // one-time R slice -> LDS (transposed to [col][k])
  for (int idx = tid; idx < 64 * 512; idx += 512) {
    int cc = idx & 63, kk = idx >> 6;
    R_s[cc * 516 + kk] = R[(size_t)kk * G4 + (cc >> 4) * 512 + u0 + (cc & 15)];
  }
  float c = 0.f;
  unsigned seq = 0;
  __syncthreads();

  for (int t = 0; t < T_; ++t) {
    {
      const float* hb = hbuf + (t & 1) * 16384 + 4 * g * 512;
      for (int i = tid; i < 2048; i += 512)
        h_st[(i >> 9) * 516 + (i & 511)] = AT_LD(&hb[i]);
    }
    __syncthreads();
    {
      const float4* H4 = (const float4*)(h_st + b_l * 516 + kh * 256);
      const float4* R4 = (const float4*)(R_s + col * 516 + kh * 256);
      float acc = 0.f;
#pragma unroll 8
      for (int i = 0; i < 64; ++i) {
        float4 hv = H4[i];
        float4 rv = R4[i];
        acc = fmaf(hv.x, rv.x, acc); acc = fmaf(hv.y, rv.y, acc);
        acc = fmaf(hv.z, rv.z, acc); acc = fmaf(hv.w, rv.w, acc);
      }
      zp[b_l][col][kh] = acc;
    }
    __syncthreads();
    if (tid < 64) {
      const int bb = tid >> 4, uu = tid & 15;
      const int b = 4 * g + bb, u = u0 + uu;
      const float* zy = Zin + ((size_t)b * T_ + t) * G4 + u;
      float zi = zy[0]    + zp[bb][uu][0]      + zp[bb][uu][1];
      float zf = zy[512]  + zp[bb][16 + uu][0] + zp[bb][16 + uu][1];
      float zg = zy[1024] + zp[bb][32 + uu][0] + zp[bb][32 + uu][1];
      float zo = zy[1536] + zp[bb][48 + uu][0] + zp[bb][48 + uu][1];
      float ig = 1.f / (1.f + expf(-zi));
      float fg = 1.f / (1.f + expf(-zf));
      float gg = tanhf(zg);
      float og = 1.f / (1.f + expf(-zo));
      c = fg * c + ig * gg;
      float hv2 = og * tanhf(c);
      AT_ST(&hbuf[((t + 1) & 1) * 16384 + b * 512 + u], hv2);
      if (seq_out) seq_out[((size_t)b * T_ + t) * U_ + u] = hv2;
      if (last_out && t == T_ - 1) last_out[b * U_ + u] = hv2;
    }
    group_bar(gflags, ggen, ++seq);
  }
}

// ---------------- decoder ----------------
__global__ __launch_bounds__(64) void final_k(
    const float* __restrict__ hT, const float* __restrict__ Wd,
    const float* __restrict__ bd, float* __restrict__ out) {
  const int b = blockIdx.x;
  const int v = threadIdx.x;
  float acc = (v < V_) ? bd[v] : -INFINITY;
  if (v < V_) {
    for (int k = 0; k < U_; ++k)
      acc = fmaf(hT[(size_t)b * U_ + k], Wd[(size_t)k * V_ + v], acc);
  }
  float m = acc;
#pragma unroll
  for (int off = 32; off; off >>= 1) m = fmaxf(m, __shfl_down(m, off));
  m = __shfl(m, 0);
  float e = (v < V_) ? expf(acc - m) : 0.f;
  float s = e;
#pragma unroll
  for (int off = 32; off; off >>= 1) s += __shfl_down(s, off);
  s = __shfl(s, 0);
  if (v < V_) out[(size_t)b * V_ + v] = e / s;
}

extern "C" void kernel_launch(void* const* d_in, const int* in_sizes, int n_in,
                              void* d_out, int out_size, void* d_ws, size_t ws_size,
                              hipStream_t stream) {
  const float* x   = (const float*)d_in[0];
  const float* y   = (const float*)d_in[1];
  const float* W_a = (const float*)d_in[2];
  const float* R_a = (const float*)d_in[3];
  const float* b_a = (const float*)d_in[4];
  const float* W1  = (const float*)d_in[5];
  const float* R1  = (const float*)d_in[6];
  const float* b1  = (const float*)d_in[7];
  const float* W2  = (const float*)d_in[8];
  const float* R2  = (const float*)d_in[9];
  const float* b2  = (const float*)d_in[10];
  const float* Wd  = (const float*)d_in[11];
  const float* bd  = (const float*)d_in[12];
  float* out = (float*)d_out;

  float* ZBUF = (float*)d_ws;                 // 8388608 f
  float* SEQ  = ZBUF + (size_t)8388608;       // 2097152 f
  float* RT   = SEQ + (size_t)2097152;        // 1048576 f
  float* HBUF = RT + (size_t)1048576;         // 32768 f
  float* HN   = HBUF + 32768;                 // 16384 f
  float* SMAX = HN + 16384;                   // 256
  float* SSUM = SMAX + 256;                   // 256
  float* CTXP = SSUM + 256;                   // 131072
  float* HT   = CTXP + 131072;                // 16384
  unsigned* BAR = (unsigned*)(HT + 16384);

  // per kernel-instance: 8 groups x (32 flags + 1 gen) x FSTR
  const int GRP = 32 * FSTR;                  // flags per group
  const int REGION = 8 * GRP + 8 * FSTR;      // 8448 u32
  unsigned* FLG_A = BAR;                 unsigned* GEN_A = FLG_A + 8 * GRP;
  unsigned* FLG_1 = BAR + REGION;        unsigned* GEN_1 = FLG_1 + 8 * GRP;
  unsigned* FLG_2 = BAR + 2 * REGION;    unsigned* GEN_2 = FLG_2 + 8 * GRP;

  const int attn_lds = (512 * 65 + 4 * 516) * 4;    // 141376 B
  const int lstm_lds = (64 * 516 + 4 * 516) * 4;    // 140352 B
  hipFuncSetAttribute((const void*)attn_coop,
                      hipFuncAttributeMaxDynamicSharedMemorySize, attn_lds);
  hipFuncSetAttribute((const void*)lstm_coop,
                      hipFuncAttributeMaxDynamicSharedMemorySize, lstm_lds);

  dim3 ggrid(2, 512);
  hipMemsetAsync(BAR, 0, 3 * REGION * 4, stream);

  gemm_k512<<<ggrid, 256, 0, stream>>>(y, W_a, b_a, ZBUF);
  transpose_R<<<dim3(32, 8), 256, 0, stream>>>(R_a, RT);
  hipMemsetAsync(HBUF, 0, 32768 * 4, stream);
  attn_coop<<<NWG, 512, attn_lds, stream>>>(x, ZBUF, RT, SEQ, HBUF, HN,
                                            SMAX, SSUM, CTXP, FLG_A, GEN_A);
  gemm_k512<<<ggrid, 256, 0, stream>>>(SEQ, W1, b1, ZBUF);
  hipMemsetAsync(HBUF, 0, 32768 * 4, stream);
  lstm_coop<<<NWG, 512, lstm_lds, stream>>>(ZBUF, R1, SEQ, nullptr, HBUF,
                                            FLG_1, GEN_1);
  gemm_k512<<<ggrid, 256, 0, stream>>>(SEQ, W2, b2, ZBUF);
  hipMemsetAsync(HBUF, 0, 32768 * 4, stream);
  lstm_coop<<<NWG, 512, lstm_lds, stream>>>(ZBUF, R2, nullptr, HT, HBUF,
                                            FLG_2, GEN_2);
  final_k<<<B_, 64, 0, stream>>>(HT, Wd, bd, out);
}

// Round 7
// 4389.190 us; speedup vs baseline: 4.5214x; 1.0514x over previous
//
#include <hip/hip_runtime.h>
#include <math.h>

// Speller round 6: 1-hop all-scan group barrier + parallel combine.
//   r5 post-mortem: barrier ~4.5 us = TWO sc1 visibility hops (arrivals ->
//   master -> gen -> pollers). v6: every WG's wave-0 scans all 32 group flags
//   itself (one visibility hop, no master serialization). Phase-D combine
//   parallelized over 512 threads (8-lane shuffle reduce) instead of 64
//   threads x 8 serial gathers.

#define U_   512
#define S_   512
#define T_   128
#define B_   32
#define G4   2048
#define V_   46
#define NWG  256
#define FSTR 32            // flag stride in u32 = 128 B

#define AT_LD(p)     __hip_atomic_load((p), __ATOMIC_RELAXED, __HIP_MEMORY_SCOPE_AGENT)
#define AT_ST(p, v)  __hip_atomic_store((p), (v), __ATOMIC_RELAXED, __HIP_MEMORY_SCOPE_AGENT)

// 1-hop barrier over the 32 WGs of this group. gflags = 32 padded slots.
__device__ __forceinline__ void group_bar(unsigned* gflags, unsigned seq) {
  __syncthreads();   // all waves' stores issued before arrival
  const int tid = threadIdx.x;
  if (tid < 32) {
    if (tid == 0)
      AT_ST(&gflags[(blockIdx.x & 31) * FSTR], seq);
    while (!__all(AT_LD(&gflags[tid * FSTR]) >= seq))
      __builtin_amdgcn_s_sleep(1);
  }
  __syncthreads();
}

// ---------------- GEMM: Z[M,2048] = A[M,512] @ W[512,2048] + b ----------------
__global__ __launch_bounds__(256) void gemm_k512(
    const float* __restrict__ A, const float* __restrict__ W,
    const float* __restrict__ b, float* __restrict__ Z) {
  const int tid = threadIdx.x;
  const int j = blockIdx.x * 1024 + tid * 4;
  const int i0 = blockIdx.y * 8;
  float4 bj = *(const float4*)(b + j);
  float4 acc[8];
#pragma unroll
  for (int r = 0; r < 8; ++r) acc[r] = bj;
  const float* Arow = A + (size_t)i0 * U_;
  for (int k = 0; k < U_; ++k) {
    float4 w = *(const float4*)(W + (size_t)k * G4 + j);
#pragma unroll
    for (int r = 0; r < 8; ++r) {
      float a = Arow[(size_t)r * U_ + k];
      acc[r].x = fmaf(a, w.x, acc[r].x);
      acc[r].y = fmaf(a, w.y, acc[r].y);
      acc[r].z = fmaf(a, w.z, acc[r].z);
      acc[r].w = fmaf(a, w.w, acc[r].w);
    }
  }
#pragma unroll
  for (int r = 0; r < 8; ++r)
    *(float4*)(Z + (size_t)(i0 + r) * G4 + j) = acc[r];
}

// ---------------- transpose R[512][2048] -> RT[2048][512] ----------------
__global__ __launch_bounds__(256) void transpose_R(
    const float* __restrict__ R, float* __restrict__ RT) {
  __shared__ float tile[64][65];
  const int c0 = blockIdx.x * 64, k0 = blockIdx.y * 64;
  const int tc = threadIdx.x & 63, tr = threadIdx.x >> 6;
  for (int r = tr; r < 64; r += 4)
    tile[r][tc] = R[(size_t)(k0 + r) * G4 + c0 + tc];
  __syncthreads();
  for (int r = tr; r < 64; r += 4)
    RT[(size_t)(c0 + r) * 512 + k0 + tc] = tile[tc][r];
}

// ---------------- attention LSTM: 8 groups x 32 WGs, 4 batches/group ------
// dyn LDS: x_s [512][65] + h_st [4][516]  = 141376 B
__global__ __launch_bounds__(512) void attn_coop(
    const float* __restrict__ x, const float* __restrict__ ZY,
    const float* __restrict__ RT, float* __restrict__ ctxs,
    float* hbuf, float* hnbuf, float* smax, float* ssumg,
    float* ctxpart, unsigned* flags) {
  extern __shared__ float dyn[];
  float* x_s  = dyn;                 // [u][65], conflict-free
  float* h_st = dyn + 512 * 65;      // [b_l][516]
  __shared__ float zp[4][64][2];
  __shared__ float hn_s[512];
  __shared__ float p_s[64];
  __shared__ float ctx_s[64];

  const int tid = threadIdx.x;
  const int bid = blockIdx.x;
  const int g    = bid >> 5;
  const int wgid = bid & 31;
  const int u0   = wgid * 16;
  // GEMV role mapping: 64 cols x 4 batches x 2 k-halves
  const int kh  = tid & 1;
  const int b_l = (tid >> 1) & 3;
  const int col = tid >> 3;                       // 0..63
  const int zcol = (col >> 4) * 512 + u0 + (col & 15);
  // attention role mapping
  const int b_att = 4 * g + (wgid >> 3);
  const int sc = wgid & 7;
  unsigned* gflags = flags + g * 32 * FSTR;

  for (int idx = tid; idx < 64 * 512; idx += 512) {
    int sl = idx >> 9, u = idx & 511;
    x_s[u * 65 + sl] = x[((size_t)b_att * S_ + sc * 64 + sl) * U_ + u];
  }
  float c = 0.f, hn_reg = 0.f;
  unsigned seq = 0;
  __syncthreads();

  for (int t = 0; t < T_; ++t) {
    // ---- stage h (8 KB, group-local batches) ----
    {
      const float* hb = hbuf + (t & 1) * 16384 + 4 * g * 512;
      for (int i = tid; i < 2048; i += 512)
        h_st[(i >> 9) * 516 + (i & 511)] = AT_LD(&hb[i]);
    }
    __syncthreads();
    // ---- GEMV: z-partial from h(LDS) x RT(L2) ----
    {
      const float4* H4 = (const float4*)(h_st + b_l * 516 + kh * 256);
      const float4* R4 = (const float4*)(RT + (size_t)zcol * 512 + kh * 256);
      float acc = 0.f;
#pragma unroll 8
      for (int i = 0; i < 64; ++i) {
        float4 hv = H4[i];
        float4 rv = R4[i];
        acc = fmaf(hv.x, rv.x, acc); acc = fmaf(hv.y, rv.y, acc);
        acc = fmaf(hv.z, rv.z, acc); acc = fmaf(hv.w, rv.w, acc);
      }
      zp[b_l][col][kh] = acc;
    }
    __syncthreads();
    if (tid < 64) {
      const int bb = tid >> 4, uu = tid & 15;
      const int b = 4 * g + bb, u = u0 + uu;
      const float* zy = ZY + ((size_t)b * T_ + t) * G4 + u;
      float zi = zy[0]    + zp[bb][uu][0]      + zp[bb][uu][1];
      float zf = zy[512]  + zp[bb][16 + uu][0] + zp[bb][16 + uu][1];
      float zg = zy[1024] + zp[bb][32 + uu][0] + zp[bb][32 + uu][1];
      float zo = zy[1536] + zp[bb][48 + uu][0] + zp[bb][48 + uu][1];
      float ig = 1.f / (1.f + expf(-zi));
      float fg = 1.f / (1.f + expf(-zf));
      float gg = tanhf(zg);
      float og = 1.f / (1.f + expf(-zo));
      c = fg * c + ig * gg;
      hn_reg = og * tanhf(c);
      AT_ST(&hnbuf[b * 512 + u], hn_reg);
    }
    group_bar(gflags, ++seq);

    // ---- scores, local softmax, ctx partials ----
    hn_s[tid] = AT_LD(&hnbuf[b_att * 512 + tid]);
    __syncthreads();
    {
      const int wv = tid >> 6, ln = tid & 63;
      for (int si = 0; si < 8; ++si) {
        const int sl = wv * 8 + si;
        float a = 0.f;
#pragma unroll
        for (int uu = ln; uu < 512; uu += 64)
          a = fmaf(hn_s[uu], x_s[uu * 65 + sl], a);
#pragma unroll
        for (int off = 32; off; off >>= 1) a += __shfl_down(a, off);
        if (ln == 0) p_s[sl] = a;
      }
    }
    __syncthreads();
    if (tid < 64) {
      float v = p_s[tid];
      float m = v;
#pragma unroll
      for (int off = 32; off; off >>= 1) m = fmaxf(m, __shfl_down(m, off));
      m = __shfl(m, 0);
      float ex = expf(v - m);
      p_s[tid] = ex;
      float sm = ex;
#pragma unroll
      for (int off = 32; off; off >>= 1) sm += __shfl_down(sm, off);
      if (tid == 0) {
        AT_ST(&smax[b_att * 8 + sc], m);
        AT_ST(&ssumg[b_att * 8 + sc], sm);
      }
    }
    __syncthreads();
    {
      float a = 0.f;
      const float* xr = x_s + tid * 65;
#pragma unroll 8
      for (int s = 0; s < 64; ++s) a = fmaf(p_s[s], xr[s], a);
      AT_ST(&ctxpart[((size_t)b_att * 8 + sc) * 512 + tid], a);
    }
    group_bar(gflags, ++seq);

    // ---- combine slices (parallel over 512 thr: pair x j) ----
    {
      const int j = tid & 7;
      const int pair = tid >> 3;            // 0..63 == gates-thread index
      const int bb = pair >> 4, uu = pair & 15;
      const int b = 4 * g + bb, u = u0 + uu;
      float lm = AT_LD(&smax[b * 8 + j]);
      float ss = AT_LD(&ssumg[b * 8 + j]);
      float cp = AT_LD(&ctxpart[((size_t)b * 8 + j) * 512 + u]);
      float gm = lm;
#pragma unroll
      for (int off = 1; off < 8; off <<= 1)
        gm = fmaxf(gm, __shfl_xor(gm, off));
      float w = expf(lm - gm);
      float st = ss * w, cs = cp * w;
#pragma unroll
      for (int off = 1; off < 8; off <<= 1) {
        st += __shfl_xor(st, off);
        cs += __shfl_xor(cs, off);
      }
      if (j == 0) ctx_s[pair] = cs / st;
    }
    __syncthreads();
    if (tid < 64) {
      const int bb = tid >> 4, uu = tid & 15;
      const int b = 4 * g + bb, u = u0 + uu;
      float ctxv = ctx_s[tid];
      c += ctxv;
      float hcar = hn_reg + ctxv;
      AT_ST(&hbuf[((t + 1) & 1) * 16384 + b * 512 + u], hcar);
      ctxs[((size_t)b * T_ + t) * U_ + u] = ctxv;
    }
    group_bar(gflags, ++seq);
  }
}

// ---------------- plain LSTM: 8 groups x 32 WGs ----------------
// dyn LDS: R_s [64][516] + h_st [4][516] = 140352 B
__global__ __launch_bounds__(512) void lstm_coop(
    const float* __restrict__ Zin, const float* __restrict__ R,
    float* __restrict__ seq_out, float* __restrict__ last_out,
    float* hbuf, unsigned* flags) {
  extern __shared__ float dyn[];
  float* R_s  = dyn;                 // [col][516]
  float* h_st = dyn + 64 * 516;      // [b_l][516]
  __shared__ float zp[4][64][2];
  const int tid = threadIdx.x;
  const int bid = blockIdx.x;
  const int g    = bid >> 5;
  const int wgid = bid & 31;
  const int u0   = wgid * 16;
  const int kh  = tid & 1;
  const int b_l = (tid >> 1) & 3;
  const int col = tid >> 3;
  unsigned* gflags = flags + g * 32 * FSTR;

  // one-time R slice -> LDS (transposed to [col][k])
  for (int idx = tid; idx < 64 * 512; idx += 512) {
    int cc = idx & 63, kk = idx >> 6;
    R_s[cc * 516 + kk] = R[(size_t)kk * G4 + (cc >> 4) * 512 + u0 + (cc & 15)];
  }
  float c = 0.f;
  unsigned seq = 0;
  __syncthreads();

  for (int t = 0; t < T_; ++t) {
    {
      const float* hb = hbuf + (t & 1) * 16384 + 4 * g * 512;
      for (int i = tid; i < 2048; i += 512)
        h_st[(i >> 9) * 516 + (i & 511)] = AT_LD(&hb[i]);
    }
    __syncthreads();
    {
      const float4* H4 = (const float4*)(h_st + b_l * 516 + kh * 256);
      const float4* R4 = (const float4*)(R_s + col * 516 + kh * 256);
      float acc = 0.f;
#pragma unroll 8
      for (int i = 0; i < 64; ++i) {
        float4 hv = H4[i];
        float4 rv = R4[i];
        acc = fmaf(hv.x, rv.x, acc); acc = fmaf(hv.y, rv.y, acc);
        acc = fmaf(hv.z, rv.z, acc); acc = fmaf(hv.w, rv.w, acc);
      }
      zp[b_l][col][kh] = acc;
    }
    __syncthreads();
    if (tid < 64) {
      const int bb = tid >> 4, uu = tid & 15;
      const int b = 4 * g + bb, u = u0 + uu;
      const float* zy = Zin + ((size_t)b * T_ + t) * G4 + u;
      float zi = zy[0]    + zp[bb][uu][0]      + zp[bb][uu][1];
      float zf = zy[512]  + zp[bb][16 + uu][0] + zp[bb][16 + uu][1];
      float zg = zy[1024] + zp[bb][32 + uu][0] + zp[bb][32 + uu][1];
      float zo = zy[1536] + zp[bb][48 + uu][0] + zp[bb][48 + uu][1];
      float ig = 1.f / (1.f + expf(-zi));
      float fg = 1.f / (1.f + expf(-zf));
      float gg = tanhf(zg);
      float og = 1.f / (1.f + expf(-zo));
      c = fg * c + ig * gg;
      float hv2 = og * tanhf(c);
      AT_ST(&hbuf[((t + 1) & 1) * 16384 + b * 512 + u], hv2);
      if (seq_out) seq_out[((size_t)b * T_ + t) * U_ + u] = hv2;
      if (last_out && t == T_ - 1) last_out[b * U_ + u] = hv2;
    }
    group_bar(gflags, ++seq);
  }
}

// ---------------- decoder ----------------
__global__ __launch_bounds__(64) void final_k(
    const float* __restrict__ hT, const float* __restrict__ Wd,
    const float* __restrict__ bd, float* __restrict__ out) {
  const int b = blockIdx.x;
  const int v = threadIdx.x;
  float acc = (v < V_) ? bd[v] : -INFINITY;
  if (v < V_) {
    for (int k = 0; k < U_; ++k)
      acc = fmaf(hT[(size_t)b * U_ + k], Wd[(size_t)k * V_ + v], acc);
  }
  float m = acc;
#pragma unroll
  for (int off = 32; off; off >>= 1) m = fmaxf(m, __shfl_down(m, off));
  m = __shfl(m, 0);
  float e = (v < V_) ? expf(acc - m) : 0.f;
  float s = e;
#pragma unroll
  for (int off = 32; off; off >>= 1) s += __shfl_down(s, off);
  s = __shfl(s, 0);
  if (v < V_) out[(size_t)b * V_ + v] = e / s;
}

extern "C" void kernel_launch(void* const* d_in, const int* in_sizes, int n_in,
                              void* d_out, int out_size, void* d_ws, size_t ws_size,
                              hipStream_t stream) {
  const float* x   = (const float*)d_in[0];
  const float* y   = (const float*)d_in[1];
  const float* W_a = (const float*)d_in[2];
  const float* R_a = (const float*)d_in[3];
  const float* b_a = (const float*)d_in[4];
  const float* W1  = (const float*)d_in[5];
  const float* R1  = (const float*)d_in[6];
  const float* b1  = (const float*)d_in[7];
  const float* W2  = (const float*)d_in[8];
  const float* R2  = (const float*)d_in[9];
  const float* b2  = (const float*)d_in[10];
  const float* Wd  = (const float*)d_in[11];
  const float* bd  = (const float*)d_in[12];
  float* out = (float*)d_out;

  float* ZBUF = (float*)d_ws;                 // 8388608 f
  float* SEQ  = ZBUF + (size_t)8388608;       // 2097152 f
  float* RT   = SEQ + (size_t)2097152;        // 1048576 f
  float* HBUF = RT + (size_t)1048576;         // 32768 f
  float* HN   = HBUF + 32768;                 // 16384 f
  float* SMAX = HN + 16384;                   // 256
  float* SSUM = SMAX + 256;                   // 256
  float* CTXP = SSUM + 256;                   // 131072
  float* HT   = CTXP + 131072;                // 16384
  unsigned* BAR = (unsigned*)(HT + 16384);

  // per kernel-instance: 8 groups x 32 flags x FSTR
  const int REGION = 8 * 32 * FSTR;           // 8192 u32
  unsigned* FLG_A = BAR;
  unsigned* FLG_1 = BAR + REGION;
  unsigned* FLG_2 = BAR + 2 * REGION;

  const int attn_lds = (512 * 65 + 4 * 516) * 4;    // 141376 B
  const int lstm_lds = (64 * 516 + 4 * 516) * 4;    // 140352 B
  hipFuncSetAttribute((const void*)attn_coop,
                      hipFuncAttributeMaxDynamicSharedMemorySize, attn_lds);
  hipFuncSetAttribute((const void*)lstm_coop,
                      hipFuncAttributeMaxDynamicSharedMemorySize, lstm_lds);

  dim3 ggrid(2, 512);
  hipMemsetAsync(BAR, 0, 3 * REGION * 4, stream);

  gemm_k512<<<ggrid, 256, 0, stream>>>(y, W_a, b_a, ZBUF);
  transpose_R<<<dim3(32, 8), 256, 0, stream>>>(R_a, RT);
  hipMemsetAsync(HBUF, 0, 32768 * 4, stream);
  attn_coop<<<NWG, 512, attn_lds, stream>>>(x, ZBUF, RT, SEQ, HBUF, HN,
                                            SMAX, SSUM, CTXP, FLG_A);
  gemm_k512<<<ggrid, 256, 0, stream>>>(SEQ, W1, b1, ZBUF);
  hipMemsetAsync(HBUF, 0, 32768 * 4, stream);
  lstm_coop<<<NWG, 512, lstm_lds, stream>>>(ZBUF, R1, SEQ, nullptr, HBUF,
                                            FLG_1);
  gemm_k512<<<ggrid, 256, 0, stream>>>(SEQ, W2, b2, ZBUF);
  hipMemsetAsync(HBUF, 0, 32768 * 4, stream);
  lstm_coop<<<NWG, 512, lstm_lds, stream>>>(ZBUF, R2, nullptr, HT, HBUF,
                                            FLG_2);
  final_k<<<B_, 64, 0, stream>>>(HT, Wd, bd, out);
}

// Round 8
// 4014.776 us; speedup vs baseline: 4.9431x; 1.0933x over previous
//
#include <hip/hip_runtime.h>
#include <math.h>

// Speller round 7: rotating exchange buffers -> cached-burst staging.
//   r6 post-mortem: ~5 us per exchange, protocol-invariant. Decomposition:
//   store drain + flag RTT + UNCACHED sc1 dword staging (2048 x 4B fabric
//   transactions per WG). v7: h/hn buffers rotate per step (slot t never
//   reused within a dispatch) so consumers use PLAIN CACHED float4 loads —
//   virgin lines always miss to the IF$ coherence point (fresh data, no
//   fences, no stale risk; dispatch-boundary acquire isolates graph replays).
//   Producers keep sc1 stores. Flags/softmax partials stay sc1 (tiny).

#define U_   512
#define S_   512
#define T_   128
#define B_   32
#define G4   2048
#define V_   46
#define NWG  256
#define FSTR 32            // flag stride in u32 = 128 B

#define AT_LD(p)     __hip_atomic_load((p), __ATOMIC_RELAXED, __HIP_MEMORY_SCOPE_AGENT)
#define AT_ST(p, v)  __hip_atomic_store((p), (v), __ATOMIC_RELAXED, __HIP_MEMORY_SCOPE_AGENT)

// 1-hop barrier over the 32 WGs of this group. gflags = 32 padded slots.
__device__ __forceinline__ void group_bar(unsigned* gflags, unsigned seq) {
  __syncthreads();   // all waves' stores drained (vmcnt) before arrival
  const int tid = threadIdx.x;
  if (tid < 32) {
    if (tid == 0)
      AT_ST(&gflags[(blockIdx.x & 31) * FSTR], seq);
    while (!__all(AT_LD(&gflags[tid * FSTR]) >= seq))
      __builtin_amdgcn_s_sleep(1);
  }
  __syncthreads();
}

// ---------------- GEMM: Z[M,2048] = A[M,512] @ W[512,2048] + b ----------------
__global__ __launch_bounds__(256) void gemm_k512(
    const float* __restrict__ A, const float* __restrict__ W,
    const float* __restrict__ b, float* __restrict__ Z) {
  const int tid = threadIdx.x;
  const int j = blockIdx.x * 1024 + tid * 4;
  const int i0 = blockIdx.y * 8;
  float4 bj = *(const float4*)(b + j);
  float4 acc[8];
#pragma unroll
  for (int r = 0; r < 8; ++r) acc[r] = bj;
  const float* Arow = A + (size_t)i0 * U_;
  for (int k = 0; k < U_; ++k) {
    float4 w = *(const float4*)(W + (size_t)k * G4 + j);
#pragma unroll
    for (int r = 0; r < 8; ++r) {
      float a = Arow[(size_t)r * U_ + k];
      acc[r].x = fmaf(a, w.x, acc[r].x);
      acc[r].y = fmaf(a, w.y, acc[r].y);
      acc[r].z = fmaf(a, w.z, acc[r].z);
      acc[r].w = fmaf(a, w.w, acc[r].w);
    }
  }
#pragma unroll
  for (int r = 0; r < 8; ++r)
    *(float4*)(Z + (size_t)(i0 + r) * G4 + j) = acc[r];
}

// ---------------- transpose R[512][2048] -> RT[2048][512] ----------------
__global__ __launch_bounds__(256) void transpose_R(
    const float* __restrict__ R, float* __restrict__ RT) {
  __shared__ float tile[64][65];
  const int c0 = blockIdx.x * 64, k0 = blockIdx.y * 64;
  const int tc = threadIdx.x & 63, tr = threadIdx.x >> 6;
  for (int r = tr; r < 64; r += 4)
    tile[r][tc] = R[(size_t)(k0 + r) * G4 + c0 + tc];
  __syncthreads();
  for (int r = tr; r < 64; r += 4)
    RT[(size_t)(c0 + r) * 512 + k0 + tc] = tile[tc][r];
}

// ---------------- attention LSTM: 8 groups x 32 WGs, 4 batches/group ------
// dyn LDS: x_s [512][65] + h_st [4][516]  = 141376 B
// hbuf: rotating [T+1][32][512]; hnbuf: rotating [T][32][512]
__global__ __launch_bounds__(512) void attn_coop(
    const float* __restrict__ x, const float* __restrict__ ZY,
    const float* __restrict__ RT, float* __restrict__ ctxs,
    float* hbuf, float* hnbuf, float* smax, float* ssumg,
    float* ctxpart, unsigned* flags) {
  extern __shared__ float dyn[];
  float* x_s  = dyn;                 // [u][65], conflict-free
  float* h_st = dyn + 512 * 65;      // [b_l][516]
  __shared__ float zp[4][64][2];
  __shared__ float hn_s[512];
  __shared__ float p_s[64];
  __shared__ float ctx_s[64];

  const int tid = threadIdx.x;
  const int bid = blockIdx.x;
  const int g    = bid >> 5;
  const int wgid = bid & 31;
  const int u0   = wgid * 16;
  // GEMV role mapping: 64 cols x 4 batches x 2 k-halves
  const int kh  = tid & 1;
  const int b_l = (tid >> 1) & 3;
  const int col = tid >> 3;                       // 0..63
  const int zcol = (col >> 4) * 512 + u0 + (col & 15);
  // attention role mapping
  const int b_att = 4 * g + (wgid >> 3);
  const int sc = wgid & 7;
  unsigned* gflags = flags + g * 32 * FSTR;

  for (int idx = tid; idx < 64 * 512; idx += 512) {
    int sl = idx >> 9, u = idx & 511;
    x_s[u * 65 + sl] = x[((size_t)b_att * S_ + sc * 64 + sl) * U_ + u];
  }
  float c = 0.f, hn_reg = 0.f;
  unsigned seq = 0;
  __syncthreads();

  for (int t = 0; t < T_; ++t) {
    // ---- stage h slot t (cached float4 burst: virgin lines -> IF$) ----
    {
      const float4* hb4 =
          (const float4*)(hbuf + (size_t)t * 16384 + 4 * g * 512);
      float4 v = hb4[tid];
      *(float4*)(h_st + (tid >> 7) * 516 + (tid & 127) * 4) = v;
    }
    __syncthreads();
    // ---- GEMV: z-partial from h(LDS) x RT(L2) ----
    {
      const float4* H4 = (const float4*)(h_st + b_l * 516 + kh * 256);
      const float4* R4 = (const float4*)(RT + (size_t)zcol * 512 + kh * 256);
      float acc = 0.f;
#pragma unroll 8
      for (int i = 0; i < 64; ++i) {
        float4 hv = H4[i];
        float4 rv = R4[i];
        acc = fmaf(hv.x, rv.x, acc); acc = fmaf(hv.y, rv.y, acc);
        acc = fmaf(hv.z, rv.z, acc); acc = fmaf(hv.w, rv.w, acc);
      }
      zp[b_l][col][kh] = acc;
    }
    __syncthreads();
    if (tid < 64) {
      const int bb = tid >> 4, uu = tid & 15;
      const int b = 4 * g + bb, u = u0 + uu;
      const float* zy = ZY + ((size_t)b * T_ + t) * G4 + u;
      float zi = zy[0]    + zp[bb][uu][0]      + zp[bb][uu][1];
      float zf = zy[512]  + zp[bb][16 + uu][0] + zp[bb][16 + uu][1];
      float zg = zy[1024] + zp[bb][32 + uu][0] + zp[bb][32 + uu][1];
      float zo = zy[1536] + zp[bb][48 + uu][0] + zp[bb][48 + uu][1];
      float ig = 1.f / (1.f + expf(-zi));
      float fg = 1.f / (1.f + expf(-zf));
      float gg = tanhf(zg);
      float og = 1.f / (1.f + expf(-zo));
      c = fg * c + ig * gg;
      hn_reg = og * tanhf(c);
      AT_ST(&hnbuf[(size_t)t * 16384 + b * 512 + u], hn_reg);
    }
    group_bar(gflags, ++seq);

    // ---- scores, local softmax, ctx partials ----
    if (tid < 128) {
      float4 v = ((const float4*)(hnbuf + (size_t)t * 16384 + b_att * 512))[tid];
      *(float4*)(hn_s + tid * 4) = v;
    }
    __syncthreads();
    {
      const int wv = tid >> 6, ln = tid & 63;
      for (int si = 0; si < 8; ++si) {
        const int sl = wv * 8 + si;
        float a = 0.f;
#pragma unroll
        for (int uu = ln; uu < 512; uu += 64)
          a = fmaf(hn_s[uu], x_s[uu * 65 + sl], a);
#pragma unroll
        for (int off = 32; off; off >>= 1) a += __shfl_down(a, off);
        if (ln == 0) p_s[sl] = a;
      }
    }
    __syncthreads();
    if (tid < 64) {
      float v = p_s[tid];
      float m = v;
#pragma unroll
      for (int off = 32; off; off >>= 1) m = fmaxf(m, __shfl_down(m, off));
      m = __shfl(m, 0);
      float ex = expf(v - m);
      p_s[tid] = ex;
      float sm = ex;
#pragma unroll
      for (int off = 32; off; off >>= 1) sm += __shfl_down(sm, off);
      if (tid == 0) {
        AT_ST(&smax[b_att * 8 + sc], m);
        AT_ST(&ssumg[b_att * 8 + sc], sm);
      }
    }
    __syncthreads();
    {
      float a = 0.f;
      const float* xr = x_s + tid * 65;
#pragma unroll 8
      for (int s = 0; s < 64; ++s) a = fmaf(p_s[s], xr[s], a);
      AT_ST(&ctxpart[((size_t)b_att * 8 + sc) * 512 + tid], a);
    }
    group_bar(gflags, ++seq);

    // ---- combine slices (parallel over 512 thr: pair x j, sc1 gathers) ----
    {
      const int j = tid & 7;
      const int pair = tid >> 3;            // 0..63 == gates-thread index
      const int bb = pair >> 4, uu = pair & 15;
      const int b = 4 * g + bb, u = u0 + uu;
      float lm = AT_LD(&smax[b * 8 + j]);
      float ss = AT_LD(&ssumg[b * 8 + j]);
      float cp = AT_LD(&ctxpart[((size_t)b * 8 + j) * 512 + u]);
      float gm = lm;
#pragma unroll
      for (int off = 1; off < 8; off <<= 1)
        gm = fmaxf(gm, __shfl_xor(gm, off));
      float w = expf(lm - gm);
      float st = ss * w, cs = cp * w;
#pragma unroll
      for (int off = 1; off < 8; off <<= 1) {
        st += __shfl_xor(st, off);
        cs += __shfl_xor(cs, off);
      }
      if (j == 0) ctx_s[pair] = cs / st;
    }
    __syncthreads();
    if (tid < 64) {
      const int bb = tid >> 4, uu = tid & 15;
      const int b = 4 * g + bb, u = u0 + uu;
      float ctxv = ctx_s[tid];
      c += ctxv;
      float hcar = hn_reg + ctxv;
      AT_ST(&hbuf[(size_t)(t + 1) * 16384 + b * 512 + u], hcar);
      ctxs[((size_t)b * T_ + t) * U_ + u] = ctxv;
    }
    group_bar(gflags, ++seq);
  }
}

// ---------------- plain LSTM: 8 groups x 32 WGs ----------------
// dyn LDS: R_s [64][516] + h_st [4][516] = 140352 B; hbuf rotating
__global__ __launch_bounds__(512) void lstm_coop(
    const float* __restrict__ Zin, const float* __restrict__ R,
    float* __restrict__ seq_out, float* __restrict__ last_out,
    float* hbuf, unsigned* flags) {
  extern __shared__ float dyn[];
  float* R_s  = dyn;                 // [col][516]
  float* h_st = dyn + 64 * 516;      // [b_l][516]
  __shared__ float zp[4][64][2];
  const int tid = threadIdx.x;
  const int bid = blockIdx.x;
  const int g    = bid >> 5;
  const int wgid = bid & 31;
  const int u0   = wgid * 16;
  const int kh  = tid & 1;
  const int b_l = (tid >> 1) & 3;
  const int col = tid >> 3;
  unsigned* gflags = flags + g * 32 * FSTR;

  // one-time R slice -> LDS (transposed to [col][k])
  for (int idx = tid; idx < 64 * 512; idx += 512) {
    int cc = idx & 63, kk = idx >> 6;
    R_s[cc * 516 + kk] = R[(size_t)kk * G4 + (cc >> 4) * 512 + u0 + (cc & 15)];
  }
  float c = 0.f;
  unsigned seq = 0;
  __syncthreads();

  for (int t = 0; t < T_; ++t) {
    {
      const float4* hb4 =
          (const float4*)(hbuf + (size_t)t * 16384 + 4 * g * 512);
      float4 v = hb4[tid];
      *(float4*)(h_st + (tid >> 7) * 516 + (tid & 127) * 4) = v;
    }
    __syncthreads();
    {
      const float4* H4 = (const float4*)(h_st + b_l * 516 + kh * 256);
      const float4* R4 = (const float4*)(R_s + col * 516 + kh * 256);
      float acc = 0.f;
#pragma unroll 8
      for (int i = 0; i < 64; ++i) {
        float4 hv = H4[i];
        float4 rv = R4[i];
        acc = fmaf(hv.x, rv.x, acc); acc = fmaf(hv.y, rv.y, acc);
        acc = fmaf(hv.z, rv.z, acc); acc = fmaf(hv.w, rv.w, acc);
      }
      zp[b_l][col][kh] = acc;
    }
    __syncthreads();
    if (tid < 64) {
      const int bb = tid >> 4, uu = tid & 15;
      const int b = 4 * g + bb, u = u0 + uu;
      const float* zy = Zin + ((size_t)b * T_ + t) * G4 + u;
      float zi = zy[0]    + zp[bb][uu][0]      + zp[bb][uu][1];
      float zf = zy[512]  + zp[bb][16 + uu][0] + zp[bb][16 + uu][1];
      float zg = zy[1024] + zp[bb][32 + uu][0] + zp[bb][32 + uu][1];
      float zo = zy[1536] + zp[bb][48 + uu][0] + zp[bb][48 + uu][1];
      float ig = 1.f / (1.f + expf(-zi));
      float fg = 1.f / (1.f + expf(-zf));
      float gg = tanhf(zg);
      float og = 1.f / (1.f + expf(-zo));
      c = fg * c + ig * gg;
      float hv2 = og * tanhf(c);
      AT_ST(&hbuf[(size_t)(t + 1) * 16384 + b * 512 + u], hv2);
      if (seq_out) seq_out[((size_t)b * T_ + t) * U_ + u] = hv2;
      if (last_out && t == T_ - 1) last_out[b * U_ + u] = hv2;
    }
    group_bar(gflags, ++seq);
  }
}

// ---------------- decoder ----------------
__global__ __launch_bounds__(64) void final_k(
    const float* __restrict__ hT, const float* __restrict__ Wd,
    const float* __restrict__ bd, float* __restrict__ out) {
  const int b = blockIdx.x;
  const int v = threadIdx.x;
  float acc = (v < V_) ? bd[v] : -INFINITY;
  if (v < V_) {
    for (int k = 0; k < U_; ++k)
      acc = fmaf(hT[(size_t)b * U_ + k], Wd[(size_t)k * V_ + v], acc);
  }
  float m = acc;
#pragma unroll
  for (int off = 32; off; off >>= 1) m = fmaxf(m, __shfl_down(m, off));
  m = __shfl(m, 0);
  float e = (v < V_) ? expf(acc - m) : 0.f;
  float s = e;
#pragma unroll
  for (int off = 32; off; off >>= 1) s += __shfl_down(s, off);
  s = __shfl(s, 0);
  if (v < V_) out[(size_t)b * V_ + v] = e / s;
}

extern "C" void kernel_launch(void* const* d_in, const int* in_sizes, int n_in,
                              void* d_out, int out_size, void* d_ws, size_t ws_size,
                              hipStream_t stream) {
  const float* x   = (const float*)d_in[0];
  const float* y   = (const float*)d_in[1];
  const float* W_a = (const float*)d_in[2];
  const float* R_a = (const float*)d_in[3];
  const float* b_a = (const float*)d_in[4];
  const float* W1  = (const float*)d_in[5];
  const float* R1  = (const float*)d_in[6];
  const float* b1  = (const float*)d_in[7];
  const float* W2  = (const float*)d_in[8];
  const float* R2  = (const float*)d_in[9];
  const float* b2  = (const float*)d_in[10];
  const float* Wd  = (const float*)d_in[11];
  const float* bd  = (const float*)d_in[12];
  float* out = (float*)d_out;

  float* ZBUF  = (float*)d_ws;                   // 8388608 f
  float* SEQ   = ZBUF + (size_t)8388608;         // 2097152 f
  float* RT    = SEQ + (size_t)2097152;          // 1048576 f
  float* HROT  = RT + (size_t)1048576;           // 129*16384 = 2113536 f
  float* HNROT = HROT + (size_t)2113536;         // 128*16384 = 2097152 f
  float* SMAX  = HNROT + (size_t)2097152;        // 256
  float* SSUM  = SMAX + 256;                     // 256
  float* CTXP  = SSUM + 256;                     // 131072
  float* HT    = CTXP + 131072;                  // 16384
  unsigned* BAR = (unsigned*)(HT + 16384);

  // per kernel-instance: 8 groups x 32 flags x FSTR
  const int REGION = 8 * 32 * FSTR;              // 8192 u32
  unsigned* FLG_A = BAR;
  unsigned* FLG_1 = BAR + REGION;
  unsigned* FLG_2 = BAR + 2 * REGION;

  const int attn_lds = (512 * 65 + 4 * 516) * 4;    // 141376 B
  const int lstm_lds = (64 * 516 + 4 * 516) * 4;    // 140352 B
  hipFuncSetAttribute((const void*)attn_coop,
                      hipFuncAttributeMaxDynamicSharedMemorySize, attn_lds);
  hipFuncSetAttribute((const void*)lstm_coop,
                      hipFuncAttributeMaxDynamicSharedMemorySize, lstm_lds);

  dim3 ggrid(2, 512);
  hipMemsetAsync(BAR, 0, 3 * REGION * 4, stream);

  gemm_k512<<<ggrid, 256, 0, stream>>>(y, W_a, b_a, ZBUF);
  transpose_R<<<dim3(32, 8), 256, 0, stream>>>(R_a, RT);
  hipMemsetAsync(HROT, 0, 16384 * 4, stream);          // h[0] = 0
  attn_coop<<<NWG, 512, attn_lds, stream>>>(x, ZBUF, RT, SEQ, HROT, HNROT,
                                            SMAX, SSUM, CTXP, FLG_A);
  gemm_k512<<<ggrid, 256, 0, stream>>>(SEQ, W1, b1, ZBUF);
  hipMemsetAsync(HROT, 0, 16384 * 4, stream);          // h1[0] = 0
  lstm_coop<<<NWG, 512, lstm_lds, stream>>>(ZBUF, R1, SEQ, nullptr, HROT,
                                            FLG_1);
  gemm_k512<<<ggrid, 256, 0, stream>>>(SEQ, W2, b2, ZBUF);
  hipMemsetAsync(HROT, 0, 16384 * 4, stream);          // h2[0] = 0
  lstm_coop<<<NWG, 512, lstm_lds, stream>>>(ZBUF, R2, nullptr, HT, HROT,
                                            FLG_2);
  final_k<<<B_, 64, 0, stream>>>(HT, Wd, bd, out);
}